// Round 1
// baseline (347.052 us; speedup 1.0000x reference)
//
#include <hip/hip_runtime.h>
#include <hip/hip_bf16.h>

#define L_SEQ 512
#define D_EMB 256
#define NH 8
#define HD 32
#define LL (L_SEQ * L_SEQ)   // 262144

__device__ __forceinline__ float bf2f(unsigned short u) {
    unsigned int x = ((unsigned int)u) << 16;
    float f;
    __builtin_memcpy(&f, &x, 4);
    return f;
}

// ---------------------------------------------------------------------------
// prep: pack per-d weights for the edge kernel.
// wpack[d][16] = { We1[0..4][d], be1[d], w2g[d][0..7], 0, 0 }
// tail[0..7] = sh[h] = sum_d g[d]*We2[d][h]
// tail[8..15] = bb[h] = sum_d b[d]*We2[d][h] + be2[h]
// ---------------------------------------------------------------------------
__global__ __launch_bounds__(256) void prep_kernel(
    const float* __restrict__ We1, const float* __restrict__ be1,
    const float* __restrict__ g,   const float* __restrict__ bta,
    const float* __restrict__ We2, const float* __restrict__ be2,
    float* __restrict__ wpack, float* __restrict__ tail)
{
    int d = threadIdx.x;  // 0..255
    float gd = g[d], bd = bta[d];
    float* row = wpack + d * 16;
    row[0] = We1[0 * 256 + d];
    row[1] = We1[1 * 256 + d];
    row[2] = We1[2 * 256 + d];
    row[3] = We1[3 * 256 + d];
    row[4] = We1[4 * 256 + d];
    row[5] = be1[d];
    float w2[8];
#pragma unroll
    for (int h = 0; h < 8; ++h) {
        w2[h] = We2[d * 8 + h];
        row[6 + h] = gd * w2[h];
    }
    row[14] = 0.f; row[15] = 0.f;

    __shared__ float red[256];
    for (int h = 0; h < 8; ++h) {
        red[d] = gd * w2[h];
        __syncthreads();
        for (int o = 128; o > 0; o >>= 1) {
            if (d < o) red[d] += red[d + o];
            __syncthreads();
        }
        if (d == 0) tail[h] = red[0];
        __syncthreads();
        red[d] = bd * w2[h];
        __syncthreads();
        for (int o = 128; o > 0; o >>= 1) {
            if (d < o) red[d] += red[d + o];
            __syncthreads();
        }
        if (d == 0) tail[8 + h] = red[0] + be2[h];
        __syncthreads();
    }
}

// ---------------------------------------------------------------------------
// gemm256: C[2048,256] = A[2048,256] @ W[256,256] + bias  (fp32, tiled)
// blockIdx.z selects one of up to 3 independent problems (QKV in one launch).
// ---------------------------------------------------------------------------
__global__ __launch_bounds__(256) void gemm256(
    const float* __restrict__ A0, const float* __restrict__ W0,
    const float* __restrict__ b0, float* __restrict__ C0,
    const float* __restrict__ A1, const float* __restrict__ W1,
    const float* __restrict__ b1, float* __restrict__ C1,
    const float* __restrict__ A2, const float* __restrict__ W2,
    const float* __restrict__ b2, float* __restrict__ C2)
{
    const float* A; const float* W; const float* bias; float* C;
    if (blockIdx.z == 0)      { A = A0; W = W0; bias = b0; C = C0; }
    else if (blockIdx.z == 1) { A = A1; W = W1; bias = b1; C = C1; }
    else                      { A = A2; W = W2; bias = b2; C = C2; }

    __shared__ float As[16][68];   // [k][m], padded
    __shared__ float Ws[16][64];   // [k][n]

    int tid = threadIdx.x;
    int bm = blockIdx.x * 64, bn = blockIdx.y * 64;
    int tm = (tid >> 4) * 4, tn = (tid & 15) * 4;
    int lr = tid >> 2, lk = (tid & 3) * 4;       // A-tile load coords
    int wr = tid >> 4, wn = (tid & 15) * 4;      // W-tile load coords

    float acc[4][4] = {};
    for (int k0 = 0; k0 < 256; k0 += 16) {
        float4 a4 = *(const float4*)(A + (size_t)(bm + lr) * 256 + k0 + lk);
        As[lk + 0][lr] = a4.x; As[lk + 1][lr] = a4.y;
        As[lk + 2][lr] = a4.z; As[lk + 3][lr] = a4.w;
        *(float4*)&Ws[wr][wn] = *(const float4*)(W + (size_t)(k0 + wr) * 256 + bn + wn);
        __syncthreads();
#pragma unroll
        for (int k = 0; k < 16; ++k) {
            float4 av = *(const float4*)&As[k][tm];
            float4 bv = *(const float4*)&Ws[k][tn];
            acc[0][0] = fmaf(av.x, bv.x, acc[0][0]);
            acc[0][1] = fmaf(av.x, bv.y, acc[0][1]);
            acc[0][2] = fmaf(av.x, bv.z, acc[0][2]);
            acc[0][3] = fmaf(av.x, bv.w, acc[0][3]);
            acc[1][0] = fmaf(av.y, bv.x, acc[1][0]);
            acc[1][1] = fmaf(av.y, bv.y, acc[1][1]);
            acc[1][2] = fmaf(av.y, bv.z, acc[1][2]);
            acc[1][3] = fmaf(av.y, bv.w, acc[1][3]);
            acc[2][0] = fmaf(av.z, bv.x, acc[2][0]);
            acc[2][1] = fmaf(av.z, bv.y, acc[2][1]);
            acc[2][2] = fmaf(av.z, bv.z, acc[2][2]);
            acc[2][3] = fmaf(av.z, bv.w, acc[2][3]);
            acc[3][0] = fmaf(av.w, bv.x, acc[3][0]);
            acc[3][1] = fmaf(av.w, bv.y, acc[3][1]);
            acc[3][2] = fmaf(av.w, bv.z, acc[3][2]);
            acc[3][3] = fmaf(av.w, bv.w, acc[3][3]);
        }
        __syncthreads();
    }
    float4 bia = *(const float4*)(bias + bn + tn);
#pragma unroll
    for (int r = 0; r < 4; ++r) {
        float4 o;
        o.x = acc[r][0] + bia.x; o.y = acc[r][1] + bia.y;
        o.z = acc[r][2] + bia.z; o.w = acc[r][3] + bia.w;
        *(float4*)(C + (size_t)(bm + tm + r) * 256 + bn + tn) = o;
    }
}

// ---------------------------------------------------------------------------
// edge_bias: for each (b,i,j) pair compute the 8 per-head additive biases
//   x = relu(ef @ We1 + be1)  (256-dim, kept in the d-loop, never stored)
//   e2[h] = (dot(x, g*We2[:,h]) - mu*sh[h]) / sigma + bb[h]
// Each thread handles 2 consecutive pairs. Output bf16 [B, H, L, L].
// ---------------------------------------------------------------------------
__global__ __launch_bounds__(256) void edge_bias(
    const float* __restrict__ EF, const float* __restrict__ wpack,
    const float* __restrict__ tail, unsigned short* __restrict__ E2)
{
    int gid = blockIdx.x * 256 + threadIdx.x;
    int p0 = gid << 1;
    int b = p0 >> 18;
    int rem = p0 & (LL - 1);
    int i = rem >> 9;
    int j = rem & (L_SEQ - 1);

    const float* efp = EF + (size_t)p0 * 5;
    float f0[5], f1[5];
#pragma unroll
    for (int e = 0; e < 5; ++e) { f0[e] = efp[e]; f1[e] = efp[5 + e]; }

    float sum0 = 0.f, sum1 = 0.f, sq0 = 0.f, sq1 = 0.f;
    float dA[8] = {}, dB[8] = {};

    for (int d = 0; d < 256; ++d) {
        const float* wrow = wpack + (d << 4);   // uniform address -> scalar loads
        float4 wa = *(const float4*)(wrow + 0);   // We1[0..3][d]
        float4 wb = *(const float4*)(wrow + 4);   // We1[4][d], be1[d], w2g0, w2g1
        float4 wc = *(const float4*)(wrow + 8);   // w2g2..5
        float4 wd = *(const float4*)(wrow + 12);  // w2g6, w2g7, 0, 0

        float x0 = fmaf(f0[0], wa.x, fmaf(f0[1], wa.y, fmaf(f0[2], wa.z,
                   fmaf(f0[3], wa.w, fmaf(f0[4], wb.x, wb.y)))));
        float x1 = fmaf(f1[0], wa.x, fmaf(f1[1], wa.y, fmaf(f1[2], wa.z,
                   fmaf(f1[3], wa.w, fmaf(f1[4], wb.x, wb.y)))));
        x0 = fmaxf(x0, 0.f); x1 = fmaxf(x1, 0.f);
        sum0 += x0; sum1 += x1;
        sq0 = fmaf(x0, x0, sq0); sq1 = fmaf(x1, x1, sq1);
        dA[0] = fmaf(x0, wb.z, dA[0]); dB[0] = fmaf(x1, wb.z, dB[0]);
        dA[1] = fmaf(x0, wb.w, dA[1]); dB[1] = fmaf(x1, wb.w, dB[1]);
        dA[2] = fmaf(x0, wc.x, dA[2]); dB[2] = fmaf(x1, wc.x, dB[2]);
        dA[3] = fmaf(x0, wc.y, dA[3]); dB[3] = fmaf(x1, wc.y, dB[3]);
        dA[4] = fmaf(x0, wc.z, dA[4]); dB[4] = fmaf(x1, wc.z, dB[4]);
        dA[5] = fmaf(x0, wc.w, dA[5]); dB[5] = fmaf(x1, wc.w, dB[5]);
        dA[6] = fmaf(x0, wd.x, dA[6]); dB[6] = fmaf(x1, wd.x, dB[6]);
        dA[7] = fmaf(x0, wd.y, dA[7]); dB[7] = fmaf(x1, wd.y, dB[7]);
    }

    const float inv256 = 1.0f / 256.0f;
    float mu0 = sum0 * inv256, mu1 = sum1 * inv256;
    float var0 = fmaf(-mu0, mu0, sq0 * inv256);
    float var1 = fmaf(-mu1, mu1, sq1 * inv256);
    float rs0 = rsqrtf(var0 + 1e-5f);
    float rs1 = rsqrtf(var1 + 1e-5f);

    float shv[8], bbv[8];
#pragma unroll
    for (int h = 0; h < 8; ++h) { shv[h] = tail[h]; bbv[h] = tail[8 + h]; }

    size_t base = ((size_t)(b * NH) * L_SEQ + i) * L_SEQ + j;
#pragma unroll
    for (int h = 0; h < 8; ++h) {
        float eA = (dA[h] - mu0 * shv[h]) * rs0 + bbv[h];
        float eB = (dB[h] - mu1 * shv[h]) * rs1 + bbv[h];
        __hip_bfloat16 ba = __float2bfloat16(eA);
        __hip_bfloat16 bbf = __float2bfloat16(eB);
        unsigned int pk = (unsigned int)(*(unsigned short*)&ba)
                        | ((unsigned int)(*(unsigned short*)&bbf) << 16);
        *(unsigned int*)(E2 + base + (size_t)h * LL) = pk;
    }
}

// ---------------------------------------------------------------------------
// attn: per block = (b,h, 16 query rows); per wave = 4 rows.
// scores (fp32, K from global/L2) -> +e2 +mask -> softmax (wave shuffles)
// -> p to LDS -> PV (V from global/L2) -> Y in [B, L, H*hd] layout.
// ---------------------------------------------------------------------------
__global__ __launch_bounds__(256) void attn_kernel(
    const float* __restrict__ Q, const float* __restrict__ K,
    const float* __restrict__ V, const unsigned short* __restrict__ E2,
    const int* __restrict__ MSK, float* __restrict__ Y)
{
    __shared__ float pbuf[4][4][520];
    int bh = blockIdx.x;
    int b = bh >> 3, h = bh & 7;
    int tid = threadIdx.x;
    int wv = __builtin_amdgcn_readfirstlane(tid >> 6);  // wave id, uniform
    int lane = tid & 63;
    int i = blockIdx.y * 16 + wv * 4;

    const float* Kb = K + (size_t)b * L_SEQ * D_EMB + h * HD;
    const float* Vb = V + (size_t)b * L_SEQ * D_EMB + h * HD;
    const float* Qb = Q + ((size_t)b * L_SEQ + i) * D_EMB + h * HD;

    float s[4][8];
#pragma unroll
    for (int r = 0; r < 4; ++r)
#pragma unroll
        for (int t = 0; t < 8; ++t) s[r][t] = 0.f;

#pragma unroll 2
    for (int d0 = 0; d0 < HD; d0 += 4) {
        float4 q0 = *(const float4*)(Qb + 0 * D_EMB + d0);
        float4 q1 = *(const float4*)(Qb + 1 * D_EMB + d0);
        float4 q2 = *(const float4*)(Qb + 2 * D_EMB + d0);
        float4 q3 = *(const float4*)(Qb + 3 * D_EMB + d0);
#pragma unroll
        for (int t = 0; t < 8; ++t) {
            int j = lane + (t << 6);
            float4 kv = *(const float4*)(Kb + (size_t)j * D_EMB + d0);
            s[0][t] = fmaf(q0.x, kv.x, fmaf(q0.y, kv.y, fmaf(q0.z, kv.z, fmaf(q0.w, kv.w, s[0][t]))));
            s[1][t] = fmaf(q1.x, kv.x, fmaf(q1.y, kv.y, fmaf(q1.z, kv.z, fmaf(q1.w, kv.w, s[1][t]))));
            s[2][t] = fmaf(q2.x, kv.x, fmaf(q2.y, kv.y, fmaf(q2.z, kv.z, fmaf(q2.w, kv.w, s[2][t]))));
            s[3][t] = fmaf(q3.x, kv.x, fmaf(q3.y, kv.y, fmaf(q3.z, kv.z, fmaf(q3.w, kv.w, s[3][t]))));
        }
    }

    const float scl = 0.17677669529663687f;  // 1/sqrt(32)
    size_t erow = ((size_t)bh * L_SEQ + i) * L_SEQ;
    size_t mrow = ((size_t)b * L_SEQ + i) * L_SEQ;

#pragma unroll
    for (int r = 0; r < 4; ++r) {
        float m = -1e30f;
#pragma unroll
        for (int t = 0; t < 8; ++t) {
            int j = lane + (t << 6);
            float e = bf2f(E2[erow + (size_t)r * L_SEQ + j]);
            int mk = MSK[mrow + (size_t)r * L_SEQ + j];
            float sv = (mk != 0) ? fmaf(s[r][t], scl, e) : -1e30f;
            s[r][t] = sv;
            m = fmaxf(m, sv);
        }
#pragma unroll
        for (int o = 32; o > 0; o >>= 1) m = fmaxf(m, __shfl_xor(m, o));
        float ssum = 0.f;
#pragma unroll
        for (int t = 0; t < 8; ++t) {
            float p = __expf(s[r][t] - m);
            s[r][t] = p;
            ssum += p;
        }
#pragma unroll
        for (int o = 32; o > 0; o >>= 1) ssum += __shfl_xor(ssum, o);
        float inv = 1.0f / ssum;
#pragma unroll
        for (int t = 0; t < 8; ++t) pbuf[wv][r][lane + (t << 6)] = s[r][t] * inv;
    }
    __syncthreads();

    // PV: lane -> (row r2 of 4, 2 consecutive d)
    int r2 = lane >> 4;
    int dd = (lane & 15) << 1;
    float yx = 0.f, yy = 0.f;
#pragma unroll 4
    for (int j = 0; j < L_SEQ; j += 4) {
        float4 p4 = *(const float4*)&pbuf[wv][r2][j];
        const float* vp = Vb + (size_t)j * D_EMB + dd;
        float2 v0 = *(const float2*)(vp);
        float2 v1 = *(const float2*)(vp + D_EMB);
        float2 v2 = *(const float2*)(vp + 2 * D_EMB);
        float2 v3 = *(const float2*)(vp + 3 * D_EMB);
        yx = fmaf(p4.x, v0.x, fmaf(p4.y, v1.x, fmaf(p4.z, v2.x, fmaf(p4.w, v3.x, yx))));
        yy = fmaf(p4.x, v0.y, fmaf(p4.y, v1.y, fmaf(p4.z, v2.y, fmaf(p4.w, v3.y, yy))));
    }
    float2 out = make_float2(yx, yy);
    *(float2*)(Y + ((size_t)b * L_SEQ + i + r2) * D_EMB + h * HD + dd) = out;
}

// ---------------------------------------------------------------------------
extern "C" void kernel_launch(void* const* d_in, const int* in_sizes, int n_in,
                              void* d_out, int out_size, void* d_ws, size_t ws_size,
                              hipStream_t stream)
{
    const float* key   = (const float*)d_in[0];
    const float* value = (const float*)d_in[1];
    const float* query = (const float*)d_in[2];
    const int*   msk   = (const int*)d_in[3];
    const float* ef    = (const float*)d_in[4];
    const float* Wk  = (const float*)d_in[5];  const float* bk  = (const float*)d_in[6];
    const float* Wq  = (const float*)d_in[7];  const float* bq  = (const float*)d_in[8];
    const float* Wv  = (const float*)d_in[9];  const float* bv  = (const float*)d_in[10];
    const float* Wp  = (const float*)d_in[11]; const float* bp  = (const float*)d_in[12];
    const float* We1 = (const float*)d_in[13]; const float* be1 = (const float*)d_in[14];
    const float* lng = (const float*)d_in[15]; const float* lnb = (const float*)d_in[16];
    const float* We2 = (const float*)d_in[17]; const float* be2 = (const float*)d_in[18];

    const int MTOK = 4 * L_SEQ;          // 2048 rows
    const int NELT = MTOK * D_EMB;       // 524288

    float* ws    = (float*)d_ws;
    float* Qw    = ws;
    float* Kw    = Qw + NELT;
    float* Vw    = Kw + NELT;
    float* Yw    = Vw + NELT;
    float* wpack = Yw + NELT;            // 4096 floats
    float* tail  = wpack + 4096;         // 16 floats
    unsigned short* E2 = (unsigned short*)(tail + 16);  // 8388608 bf16 (~16.8 MB)

    hipLaunchKernelGGL(prep_kernel, dim3(1), dim3(256), 0, stream,
                       We1, be1, lng, lnb, We2, be2, wpack, tail);
    hipLaunchKernelGGL(gemm256, dim3(32, 4, 3), dim3(256), 0, stream,
                       query, Wq, bq, Qw,
                       key,   Wk, bk, Kw,
                       value, Wv, bv, Vw);
    hipLaunchKernelGGL(edge_bias, dim3(2048), dim3(256), 0, stream,
                       ef, wpack, tail, E2);
    hipLaunchKernelGGL(attn_kernel, dim3(32, 32), dim3(256), 0, stream,
                       Qw, Kw, Vw, E2, msk, Yw);
    hipLaunchKernelGGL(gemm256, dim3(32, 4, 1), dim3(256), 0, stream,
                       Yw, Wp, bp, (float*)d_out,
                       Yw, Wp, bp, (float*)d_out,
                       Yw, Wp, bp, (float*)d_out);
}

// Round 2
// 330.689 us; speedup vs baseline: 1.0495x; 1.0495x over previous
//
#include <hip/hip_runtime.h>
#include <hip/hip_bf16.h>

#define L_SEQ 512
#define D_EMB 256
#define NH 8
#define HD 32
#define LL (L_SEQ * L_SEQ)   // 262144

__device__ __forceinline__ float bf2f(unsigned short u) {
    unsigned int x = ((unsigned int)u) << 16;
    float f;
    __builtin_memcpy(&f, &x, 4);
    return f;
}

// ---------------------------------------------------------------------------
// prep: pack per-d weights for the edge kernel.
// wpack[d][16] = { We1[0..4][d], be1[d], w2g[d][0..7], 0, 0 }
// tail[0..7] = sh[h] = sum_d g[d]*We2[d][h]
// tail[8..15] = bb[h] = sum_d b[d]*We2[d][h] + be2[h]
// ---------------------------------------------------------------------------
__global__ __launch_bounds__(256) void prep_kernel(
    const float* __restrict__ We1, const float* __restrict__ be1,
    const float* __restrict__ g,   const float* __restrict__ bta,
    const float* __restrict__ We2, const float* __restrict__ be2,
    float* __restrict__ wpack, float* __restrict__ tail)
{
    int d = threadIdx.x;  // 0..255
    float gd = g[d], bd = bta[d];
    float* row = wpack + d * 16;
    row[0] = We1[0 * 256 + d];
    row[1] = We1[1 * 256 + d];
    row[2] = We1[2 * 256 + d];
    row[3] = We1[3 * 256 + d];
    row[4] = We1[4 * 256 + d];
    row[5] = be1[d];
    float w2[8];
#pragma unroll
    for (int h = 0; h < 8; ++h) {
        w2[h] = We2[d * 8 + h];
        row[6 + h] = gd * w2[h];
    }
    row[14] = 0.f; row[15] = 0.f;

    __shared__ float red[256];
    for (int h = 0; h < 8; ++h) {
        red[d] = gd * w2[h];
        __syncthreads();
        for (int o = 128; o > 0; o >>= 1) {
            if (d < o) red[d] += red[d + o];
            __syncthreads();
        }
        if (d == 0) tail[h] = red[0];
        __syncthreads();
        red[d] = bd * w2[h];
        __syncthreads();
        for (int o = 128; o > 0; o >>= 1) {
            if (d < o) red[d] += red[d + o];
            __syncthreads();
        }
        if (d == 0) tail[8 + h] = red[0] + be2[h];
        __syncthreads();
    }
}

// ---------------------------------------------------------------------------
// gemm256: C[2048,256] = A[2048,256] @ W[256,256] + bias  (fp32, tiled)
// blockIdx.z selects one of up to 3 independent problems (QKV in one launch).
// ---------------------------------------------------------------------------
__global__ __launch_bounds__(256) void gemm256(
    const float* __restrict__ A0, const float* __restrict__ W0,
    const float* __restrict__ b0, float* __restrict__ C0,
    const float* __restrict__ A1, const float* __restrict__ W1,
    const float* __restrict__ b1, float* __restrict__ C1,
    const float* __restrict__ A2, const float* __restrict__ W2,
    const float* __restrict__ b2, float* __restrict__ C2)
{
    const float* A; const float* W; const float* bias; float* C;
    if (blockIdx.z == 0)      { A = A0; W = W0; bias = b0; C = C0; }
    else if (blockIdx.z == 1) { A = A1; W = W1; bias = b1; C = C1; }
    else                      { A = A2; W = W2; bias = b2; C = C2; }

    __shared__ float As[16][68];   // [k][m], padded
    __shared__ float Ws[16][64];   // [k][n]

    int tid = threadIdx.x;
    int bm = blockIdx.x * 64, bn = blockIdx.y * 64;
    int tm = (tid >> 4) * 4, tn = (tid & 15) * 4;
    int lr = tid >> 2, lk = (tid & 3) * 4;       // A-tile load coords
    int wr = tid >> 4, wn = (tid & 15) * 4;      // W-tile load coords

    float acc[4][4] = {};
    for (int k0 = 0; k0 < 256; k0 += 16) {
        float4 a4 = *(const float4*)(A + (size_t)(bm + lr) * 256 + k0 + lk);
        As[lk + 0][lr] = a4.x; As[lk + 1][lr] = a4.y;
        As[lk + 2][lr] = a4.z; As[lk + 3][lr] = a4.w;
        *(float4*)&Ws[wr][wn] = *(const float4*)(W + (size_t)(k0 + wr) * 256 + bn + wn);
        __syncthreads();
#pragma unroll
        for (int k = 0; k < 16; ++k) {
            float4 av = *(const float4*)&As[k][tm];
            float4 bv = *(const float4*)&Ws[k][tn];
            acc[0][0] = fmaf(av.x, bv.x, acc[0][0]);
            acc[0][1] = fmaf(av.x, bv.y, acc[0][1]);
            acc[0][2] = fmaf(av.x, bv.z, acc[0][2]);
            acc[0][3] = fmaf(av.x, bv.w, acc[0][3]);
            acc[1][0] = fmaf(av.y, bv.x, acc[1][0]);
            acc[1][1] = fmaf(av.y, bv.y, acc[1][1]);
            acc[1][2] = fmaf(av.y, bv.z, acc[1][2]);
            acc[1][3] = fmaf(av.y, bv.w, acc[1][3]);
            acc[2][0] = fmaf(av.z, bv.x, acc[2][0]);
            acc[2][1] = fmaf(av.z, bv.y, acc[2][1]);
            acc[2][2] = fmaf(av.z, bv.z, acc[2][2]);
            acc[2][3] = fmaf(av.z, bv.w, acc[2][3]);
            acc[3][0] = fmaf(av.w, bv.x, acc[3][0]);
            acc[3][1] = fmaf(av.w, bv.y, acc[3][1]);
            acc[3][2] = fmaf(av.w, bv.z, acc[3][2]);
            acc[3][3] = fmaf(av.w, bv.w, acc[3][3]);
        }
        __syncthreads();
    }
    float4 bia = *(const float4*)(bias + bn + tn);
#pragma unroll
    for (int r = 0; r < 4; ++r) {
        float4 o;
        o.x = acc[r][0] + bia.x; o.y = acc[r][1] + bia.y;
        o.z = acc[r][2] + bia.z; o.w = acc[r][3] + bia.w;
        *(float4*)(C + (size_t)(bm + tm + r) * 256 + bn + tn) = o;
    }
}

// ---------------------------------------------------------------------------
// transpose_k: Kw [B*L, 256] -> Kt [B, H, HD, L]  (per (b,h): 512x32 -> 32x512)
// so attention QK^T loads are lane-coalesced along L.
// ---------------------------------------------------------------------------
__global__ __launch_bounds__(256) void transpose_k(
    const float* __restrict__ Kw, float* __restrict__ Kt)
{
    __shared__ float tile[128][33];
    int bh = blockIdx.x;          // 0..31
    int b = bh >> 3, h = bh & 7;
    int l0 = blockIdx.y * 128;
    int tid = threadIdx.x;

    int tr = tid >> 3;            // 0..31
    int tc = (tid & 7) * 4;       // 0,4,...,28
#pragma unroll
    for (int p = 0; p < 4; ++p) {
        int ll = p * 32 + tr;
        float4 v = *(const float4*)(Kw + ((size_t)(b * L_SEQ + l0 + ll)) * 256 + h * HD + tc);
        tile[ll][tc + 0] = v.x; tile[ll][tc + 1] = v.y;
        tile[ll][tc + 2] = v.z; tile[ll][tc + 3] = v.w;
    }
    __syncthreads();

    float* out = Kt + (size_t)bh * (HD * L_SEQ);
#pragma unroll
    for (int it = 0; it < 16; ++it) {
        int flat = it * 256 + tid;
        int d = flat >> 7;        // 0..31
        int l = flat & 127;
        out[(size_t)d * L_SEQ + l0 + l] = tile[l][d];
    }
}

// ---------------------------------------------------------------------------
// edge_bias: for each (b,i,j) pair compute the 8 per-head additive biases
//   x = relu(ef @ We1 + be1)  (256-dim, kept in the d-loop, never stored)
//   e2[h] = (dot(x, g*We2[:,h]) - mu*sh[h]) / sigma + bb[h]
// Each thread handles 2 consecutive pairs. Output bf16 [B, H, L, L].
// ---------------------------------------------------------------------------
__global__ __launch_bounds__(256) void edge_bias(
    const float* __restrict__ EF, const float* __restrict__ wpack,
    const float* __restrict__ tail, unsigned short* __restrict__ E2)
{
    int gid = blockIdx.x * 256 + threadIdx.x;
    int p0 = gid << 1;
    int b = p0 >> 18;
    int rem = p0 & (LL - 1);
    int i = rem >> 9;
    int j = rem & (L_SEQ - 1);

    const float* efp = EF + (size_t)p0 * 5;
    float f0[5], f1[5];
#pragma unroll
    for (int e = 0; e < 5; ++e) { f0[e] = efp[e]; f1[e] = efp[5 + e]; }

    float sum0 = 0.f, sum1 = 0.f, sq0 = 0.f, sq1 = 0.f;
    float dA[8] = {}, dB[8] = {};

    for (int d = 0; d < 256; ++d) {
        const float* wrow = wpack + (d << 4);   // uniform address -> scalar loads
        float4 wa = *(const float4*)(wrow + 0);   // We1[0..3][d]
        float4 wb = *(const float4*)(wrow + 4);   // We1[4][d], be1[d], w2g0, w2g1
        float4 wc = *(const float4*)(wrow + 8);   // w2g2..5
        float4 wd = *(const float4*)(wrow + 12);  // w2g6, w2g7, 0, 0

        float x0 = fmaf(f0[0], wa.x, fmaf(f0[1], wa.y, fmaf(f0[2], wa.z,
                   fmaf(f0[3], wa.w, fmaf(f0[4], wb.x, wb.y)))));
        float x1 = fmaf(f1[0], wa.x, fmaf(f1[1], wa.y, fmaf(f1[2], wa.z,
                   fmaf(f1[3], wa.w, fmaf(f1[4], wb.x, wb.y)))));
        x0 = fmaxf(x0, 0.f); x1 = fmaxf(x1, 0.f);
        sum0 += x0; sum1 += x1;
        sq0 = fmaf(x0, x0, sq0); sq1 = fmaf(x1, x1, sq1);
        dA[0] = fmaf(x0, wb.z, dA[0]); dB[0] = fmaf(x1, wb.z, dB[0]);
        dA[1] = fmaf(x0, wb.w, dA[1]); dB[1] = fmaf(x1, wb.w, dB[1]);
        dA[2] = fmaf(x0, wc.x, dA[2]); dB[2] = fmaf(x1, wc.x, dB[2]);
        dA[3] = fmaf(x0, wc.y, dA[3]); dB[3] = fmaf(x1, wc.y, dB[3]);
        dA[4] = fmaf(x0, wc.z, dA[4]); dB[4] = fmaf(x1, wc.z, dB[4]);
        dA[5] = fmaf(x0, wc.w, dA[5]); dB[5] = fmaf(x1, wc.w, dB[5]);
        dA[6] = fmaf(x0, wd.x, dA[6]); dB[6] = fmaf(x1, wd.x, dB[6]);
        dA[7] = fmaf(x0, wd.y, dA[7]); dB[7] = fmaf(x1, wd.y, dB[7]);
    }

    const float inv256 = 1.0f / 256.0f;
    float mu0 = sum0 * inv256, mu1 = sum1 * inv256;
    float var0 = fmaf(-mu0, mu0, sq0 * inv256);
    float var1 = fmaf(-mu1, mu1, sq1 * inv256);
    float rs0 = rsqrtf(var0 + 1e-5f);
    float rs1 = rsqrtf(var1 + 1e-5f);

    float shv[8], bbv[8];
#pragma unroll
    for (int h = 0; h < 8; ++h) { shv[h] = tail[h]; bbv[h] = tail[8 + h]; }

    size_t base = ((size_t)(b * NH) * L_SEQ + i) * L_SEQ + j;
#pragma unroll
    for (int h = 0; h < 8; ++h) {
        float eA = (dA[h] - mu0 * shv[h]) * rs0 + bbv[h];
        float eB = (dB[h] - mu1 * shv[h]) * rs1 + bbv[h];
        __hip_bfloat16 ba = __float2bfloat16(eA);
        __hip_bfloat16 bbf = __float2bfloat16(eB);
        unsigned int pk = (unsigned int)(*(unsigned short*)&ba)
                        | ((unsigned int)(*(unsigned short*)&bbf) << 16);
        *(unsigned int*)(E2 + base + (size_t)h * LL) = pk;
    }
}

// ---------------------------------------------------------------------------
// attn: per block = (b,h, 16 query rows); per wave = 4 rows.
// QK^T now reads Kt[B,H,HD,L] -> lane-coalesced dword loads (was 1KB-strided).
// Q staged to LDS (broadcast reads). Softmax / E2 / mask / PV unchanged.
// ---------------------------------------------------------------------------
__global__ __launch_bounds__(256) void attn_kernel(
    const float* __restrict__ Q, const float* __restrict__ Kt,
    const float* __restrict__ V, const unsigned short* __restrict__ E2,
    const int* __restrict__ MSK, float* __restrict__ Y)
{
    __shared__ float pbuf[4][4][520];
    __shared__ float qs[16][33];
    int bh = blockIdx.x;
    int b = bh >> 3, h = bh & 7;
    int tid = threadIdx.x;
    int wv = __builtin_amdgcn_readfirstlane(tid >> 6);  // wave id, uniform
    int lane = tid & 63;
    int i0 = blockIdx.y * 16;
    int i = i0 + wv * 4;

    // stage the 16 Q rows (32 dims each) for this block
    if (tid < 128) {
        int r = tid >> 3;            // 0..15
        int c = (tid & 7) * 4;       // 0..28
        float4 qv = *(const float4*)(Q + ((size_t)(b * L_SEQ + i0 + r)) * 256 + h * HD + c);
        qs[r][c + 0] = qv.x; qs[r][c + 1] = qv.y;
        qs[r][c + 2] = qv.z; qs[r][c + 3] = qv.w;
    }
    __syncthreads();

    const float* Ktb = Kt + (size_t)bh * (HD * L_SEQ);
    const float* Vb = V + (size_t)b * L_SEQ * D_EMB + h * HD;

    float s[4][8];
#pragma unroll
    for (int r = 0; r < 4; ++r)
#pragma unroll
        for (int t = 0; t < 8; ++t) s[r][t] = 0.f;

#pragma unroll 2
    for (int d = 0; d < HD; ++d) {
        float q0 = qs[wv * 4 + 0][d];
        float q1 = qs[wv * 4 + 1][d];
        float q2 = qs[wv * 4 + 2][d];
        float q3 = qs[wv * 4 + 3][d];
        const float* kp = Ktb + (size_t)d * L_SEQ + lane;
#pragma unroll
        for (int t = 0; t < 8; ++t) {
            float kv = kp[t << 6];
            s[0][t] = fmaf(q0, kv, s[0][t]);
            s[1][t] = fmaf(q1, kv, s[1][t]);
            s[2][t] = fmaf(q2, kv, s[2][t]);
            s[3][t] = fmaf(q3, kv, s[3][t]);
        }
    }

    const float scl = 0.17677669529663687f;  // 1/sqrt(32)
    size_t erow = ((size_t)bh * L_SEQ + i) * L_SEQ;
    size_t mrow = ((size_t)b * L_SEQ + i) * L_SEQ;

#pragma unroll
    for (int r = 0; r < 4; ++r) {
        float m = -1e30f;
#pragma unroll
        for (int t = 0; t < 8; ++t) {
            int j = lane + (t << 6);
            float e = bf2f(E2[erow + (size_t)r * L_SEQ + j]);
            int mk = MSK[mrow + (size_t)r * L_SEQ + j];
            float sv = (mk != 0) ? fmaf(s[r][t], scl, e) : -1e30f;
            s[r][t] = sv;
            m = fmaxf(m, sv);
        }
#pragma unroll
        for (int o = 32; o > 0; o >>= 1) m = fmaxf(m, __shfl_xor(m, o));
        float ssum = 0.f;
#pragma unroll
        for (int t = 0; t < 8; ++t) {
            float p = __expf(s[r][t] - m);
            s[r][t] = p;
            ssum += p;
        }
#pragma unroll
        for (int o = 32; o > 0; o >>= 1) ssum += __shfl_xor(ssum, o);
        float inv = 1.0f / ssum;
#pragma unroll
        for (int t = 0; t < 8; ++t) pbuf[wv][r][lane + (t << 6)] = s[r][t] * inv;
    }
    __syncthreads();

    // PV: lane -> (row r2 of 4, 2 consecutive d)
    int r2 = lane >> 4;
    int dd = (lane & 15) << 1;
    float yx = 0.f, yy = 0.f;
#pragma unroll 4
    for (int j = 0; j < L_SEQ; j += 4) {
        float4 p4 = *(const float4*)&pbuf[wv][r2][j];
        const float* vp = Vb + (size_t)j * D_EMB + dd;
        float2 v0 = *(const float2*)(vp);
        float2 v1 = *(const float2*)(vp + D_EMB);
        float2 v2 = *(const float2*)(vp + 2 * D_EMB);
        float2 v3 = *(const float2*)(vp + 3 * D_EMB);
        yx = fmaf(p4.x, v0.x, fmaf(p4.y, v1.x, fmaf(p4.z, v2.x, fmaf(p4.w, v3.x, yx))));
        yy = fmaf(p4.x, v0.y, fmaf(p4.y, v1.y, fmaf(p4.z, v2.y, fmaf(p4.w, v3.y, yy))));
    }
    float2 out = make_float2(yx, yy);
    *(float2*)(Y + ((size_t)b * L_SEQ + i + r2) * D_EMB + h * HD + dd) = out;
}

// ---------------------------------------------------------------------------
extern "C" void kernel_launch(void* const* d_in, const int* in_sizes, int n_in,
                              void* d_out, int out_size, void* d_ws, size_t ws_size,
                              hipStream_t stream)
{
    const float* key   = (const float*)d_in[0];
    const float* value = (const float*)d_in[1];
    const float* query = (const float*)d_in[2];
    const int*   msk   = (const int*)d_in[3];
    const float* ef    = (const float*)d_in[4];
    const float* Wk  = (const float*)d_in[5];  const float* bk  = (const float*)d_in[6];
    const float* Wq  = (const float*)d_in[7];  const float* bq  = (const float*)d_in[8];
    const float* Wv  = (const float*)d_in[9];  const float* bv  = (const float*)d_in[10];
    const float* Wp  = (const float*)d_in[11]; const float* bp  = (const float*)d_in[12];
    const float* We1 = (const float*)d_in[13]; const float* be1 = (const float*)d_in[14];
    const float* lng = (const float*)d_in[15]; const float* lnb = (const float*)d_in[16];
    const float* We2 = (const float*)d_in[17]; const float* be2 = (const float*)d_in[18];

    const int MTOK = 4 * L_SEQ;          // 2048 rows
    const int NELT = MTOK * D_EMB;       // 524288

    float* ws    = (float*)d_ws;
    float* Qw    = ws;
    float* Kw    = Qw + NELT;
    float* Vw    = Kw + NELT;
    float* Yw    = Vw + NELT;
    float* Ktw   = Yw + NELT;            // transposed K, 524288 floats
    float* wpack = Ktw + NELT;           // 4096 floats
    float* tail  = wpack + 4096;         // 16 floats
    unsigned short* E2 = (unsigned short*)(tail + 16);  // 8388608 bf16 (~16.8 MB)

    hipLaunchKernelGGL(prep_kernel, dim3(1), dim3(256), 0, stream,
                       We1, be1, lng, lnb, We2, be2, wpack, tail);
    hipLaunchKernelGGL(gemm256, dim3(32, 4, 3), dim3(256), 0, stream,
                       query, Wq, bq, Qw,
                       key,   Wk, bk, Kw,
                       value, Wv, bv, Vw);
    hipLaunchKernelGGL(transpose_k, dim3(32, 4), dim3(256), 0, stream,
                       Kw, Ktw);
    hipLaunchKernelGGL(edge_bias, dim3(2048), dim3(256), 0, stream,
                       ef, wpack, tail, E2);
    hipLaunchKernelGGL(attn_kernel, dim3(32, 32), dim3(256), 0, stream,
                       Qw, Ktw, Vw, E2, msk, Yw);
    hipLaunchKernelGGL(gemm256, dim3(32, 4, 1), dim3(256), 0, stream,
                       Yw, Wp, bp, (float*)d_out,
                       Yw, Wp, bp, (float*)d_out,
                       Yw, Wp, bp, (float*)d_out);
}

// Round 3
// 308.961 us; speedup vs baseline: 1.1233x; 1.0703x over previous
//
#include <hip/hip_runtime.h>
#include <hip/hip_bf16.h>

#define L_SEQ 512
#define D_EMB 256
#define NH 8
#define HD 32
#define LL (L_SEQ * L_SEQ)   // 262144

typedef __attribute__((ext_vector_type(8))) short short8;
typedef __attribute__((ext_vector_type(4))) float f32x4;
typedef unsigned short ushort;

__device__ __forceinline__ float bf2f(ushort u) {
    unsigned int x = ((unsigned int)u) << 16;
    float f;
    __builtin_memcpy(&f, &x, 4);
    return f;
}
__device__ __forceinline__ ushort f2bf(float x) {
    __hip_bfloat16 h = __float2bfloat16(x);
    ushort u;
    __builtin_memcpy(&u, &h, 2);
    return u;
}

// ---------------------------------------------------------------------------
// prep: build MFMA fragment tables for the edge kernel + LN-fold tails.
//
// Stage-A A-operand table W1G[tile][lane][j] (16x64x8 bf16):
//   A = W1aug [m=d_local 16][k 32], lane: m=lane&15, k=(lane>>4)*8+j
//   k 0-4  : hi(We1[k][d])      k 5-9 : lo(We1[k-5][d])
//   k 10-14: hi(We1[k-10][d])   k 15  : hi(be1[d])   k 16: lo(be1[d])  else 0
// Stage-B B-operand table B2G[kc][lane][j] (8x64x8 bf16):
//   B2[k=d][n], lane: n=lane&15, k=kc*32+(lane>>4)*8+j
//   n 0-7: hi(g[d]*We2[d][n])   n 8-15: lo(g[d]*We2[d][n-8])
// tail[0..7]=sh[h]=sum_d g*We2 ; tail[8..15]=bb[h]=sum_d b*We2 + be2 ; 16..31=0
// ---------------------------------------------------------------------------
__global__ __launch_bounds__(256) void prep_kernel(
    const float* __restrict__ We1, const float* __restrict__ be1,
    const float* __restrict__ g,   const float* __restrict__ bta,
    const float* __restrict__ We2, const float* __restrict__ be2,
    ushort* __restrict__ W1G, ushort* __restrict__ B2G, float* __restrict__ tail)
{
    int t = threadIdx.x;  // 0..255
    __shared__ float red[16][256];
    float gd = g[t], bd = bta[t];
#pragma unroll
    for (int h = 0; h < 8; ++h) {
        float w2 = We2[t * 8 + h];
        red[h][t] = gd * w2;
        red[8 + h][t] = bd * w2;
    }
    __syncthreads();
    for (int off = 128; off > 0; off >>= 1) {
        if (t < off) {
#pragma unroll
            for (int row = 0; row < 16; ++row) red[row][t] += red[row][t + off];
        }
        __syncthreads();
    }
    if (t < 8) {
        tail[t] = red[t][0];
        tail[8 + t] = red[8 + t][0] + be2[t];
    }
    if (t >= 16 && t < 32) tail[t] = 0.f;

    // W1G: 8192 entries
    for (int idx = t; idx < 8192; idx += 256) {
        int j = idx & 7, lane = (idx >> 3) & 63, tile = idx >> 9;
        int m = lane & 15, q = lane >> 4;
        int k = q * 8 + j;
        int d = tile * 16 + m;
        float v = 0.f;
        bool lo = false;
        if (k < 5)        v = We1[k * 256 + d];
        else if (k < 10)  { v = We1[(k - 5) * 256 + d]; lo = true; }
        else if (k < 15)  v = We1[(k - 10) * 256 + d];
        else if (k == 15) v = be1[d];
        else if (k == 16) { v = be1[d]; lo = true; }
        ushort hi = f2bf(v);
        W1G[idx] = lo ? f2bf(v - bf2f(hi)) : hi;
    }
    // B2G: 4096 entries
    for (int idx = t; idx < 4096; idx += 256) {
        int j = idx & 7, lane = (idx >> 3) & 63, kc = idx >> 9;
        int n = lane & 15, q = lane >> 4;
        int d = kc * 32 + q * 8 + j;
        float w = g[d] * We2[d * 8 + (n & 7)];
        ushort hi = f2bf(w);
        B2G[idx] = (n < 8) ? hi : f2bf(w - bf2f(hi));
    }
}

// ---------------------------------------------------------------------------
// gemm256: C[2048,256] = A[2048,256] @ W[256,256] + bias  (fp32, tiled)
// ---------------------------------------------------------------------------
__global__ __launch_bounds__(256) void gemm256(
    const float* __restrict__ A0, const float* __restrict__ W0,
    const float* __restrict__ b0, float* __restrict__ C0,
    const float* __restrict__ A1, const float* __restrict__ W1,
    const float* __restrict__ b1, float* __restrict__ C1,
    const float* __restrict__ A2, const float* __restrict__ W2,
    const float* __restrict__ b2, float* __restrict__ C2)
{
    const float* A; const float* W; const float* bias; float* C;
    if (blockIdx.z == 0)      { A = A0; W = W0; bias = b0; C = C0; }
    else if (blockIdx.z == 1) { A = A1; W = W1; bias = b1; C = C1; }
    else                      { A = A2; W = W2; bias = b2; C = C2; }

    __shared__ float As[16][68];
    __shared__ float Ws[16][64];

    int tid = threadIdx.x;
    int bm = blockIdx.x * 64, bn = blockIdx.y * 64;
    int tm = (tid >> 4) * 4, tn = (tid & 15) * 4;
    int lr = tid >> 2, lk = (tid & 3) * 4;
    int wr = tid >> 4, wn = (tid & 15) * 4;

    float acc[4][4] = {};
    for (int k0 = 0; k0 < 256; k0 += 16) {
        float4 a4 = *(const float4*)(A + (size_t)(bm + lr) * 256 + k0 + lk);
        As[lk + 0][lr] = a4.x; As[lk + 1][lr] = a4.y;
        As[lk + 2][lr] = a4.z; As[lk + 3][lr] = a4.w;
        *(float4*)&Ws[wr][wn] = *(const float4*)(W + (size_t)(k0 + wr) * 256 + bn + wn);
        __syncthreads();
#pragma unroll
        for (int k = 0; k < 16; ++k) {
            float4 av = *(const float4*)&As[k][tm];
            float4 bv = *(const float4*)&Ws[k][tn];
            acc[0][0] = fmaf(av.x, bv.x, acc[0][0]);
            acc[0][1] = fmaf(av.x, bv.y, acc[0][1]);
            acc[0][2] = fmaf(av.x, bv.z, acc[0][2]);
            acc[0][3] = fmaf(av.x, bv.w, acc[0][3]);
            acc[1][0] = fmaf(av.y, bv.x, acc[1][0]);
            acc[1][1] = fmaf(av.y, bv.y, acc[1][1]);
            acc[1][2] = fmaf(av.y, bv.z, acc[1][2]);
            acc[1][3] = fmaf(av.y, bv.w, acc[1][3]);
            acc[2][0] = fmaf(av.z, bv.x, acc[2][0]);
            acc[2][1] = fmaf(av.z, bv.y, acc[2][1]);
            acc[2][2] = fmaf(av.z, bv.z, acc[2][2]);
            acc[2][3] = fmaf(av.z, bv.w, acc[2][3]);
            acc[3][0] = fmaf(av.w, bv.x, acc[3][0]);
            acc[3][1] = fmaf(av.w, bv.y, acc[3][1]);
            acc[3][2] = fmaf(av.w, bv.z, acc[3][2]);
            acc[3][3] = fmaf(av.w, bv.w, acc[3][3]);
        }
        __syncthreads();
    }
    float4 bia = *(const float4*)(bias + bn + tn);
#pragma unroll
    for (int r = 0; r < 4; ++r) {
        float4 o;
        o.x = acc[r][0] + bia.x; o.y = acc[r][1] + bia.y;
        o.z = acc[r][2] + bia.z; o.w = acc[r][3] + bia.w;
        *(float4*)(C + (size_t)(bm + tm + r) * 256 + bn + tn) = o;
    }
}

// ---------------------------------------------------------------------------
// transpose_k: Kw [B*L, 256] -> Kt [B, H, HD, L]
// ---------------------------------------------------------------------------
__global__ __launch_bounds__(256) void transpose_k(
    const float* __restrict__ Kw, float* __restrict__ Kt)
{
    __shared__ float tile[128][33];
    int bh = blockIdx.x;
    int b = bh >> 3, h = bh & 7;
    int l0 = blockIdx.y * 128;
    int tid = threadIdx.x;

    int tr = tid >> 3;
    int tc = (tid & 7) * 4;
#pragma unroll
    for (int p = 0; p < 4; ++p) {
        int ll = p * 32 + tr;
        float4 v = *(const float4*)(Kw + ((size_t)(b * L_SEQ + l0 + ll)) * 256 + h * HD + tc);
        tile[ll][tc + 0] = v.x; tile[ll][tc + 1] = v.y;
        tile[ll][tc + 2] = v.z; tile[ll][tc + 3] = v.w;
    }
    __syncthreads();

    float* out = Kt + (size_t)bh * (HD * L_SEQ);
#pragma unroll
    for (int it = 0; it < 16; ++it) {
        int flat = it * 256 + tid;
        int d = flat >> 7;
        int l = flat & 127;
        out[(size_t)d * L_SEQ + l0 + l] = tile[l][d];
    }
}

// ---------------------------------------------------------------------------
// edge_bias_mfma: per block = one (b,i) row (512 j's), 8 iters x 64 pairs.
// Per wave-iter: 16 pairs x 256 d.
//  Stage A: 16x MFMA(16x16x32 bf16): X = relu(EFaug @ W1aug) exact via hi/lo.
//           D layout gives lane 4 consecutive d per pair -> relu, sum/sq (fp32),
//           cvt bf16, ds_write_b64 into per-wave X tile (no barriers).
//  Stage B: 8x MFMA over K=256: dots = X @ [w2g_hi | w2g_lo]; dot=hi+lo via shfl.
//  Epilogue: LN fold: e2 = (dot - mu*sh)*rs + bb -> bf16 E2[B,H,L,L].
// ---------------------------------------------------------------------------
__global__ __launch_bounds__(256) void edge_bias_mfma(
    const float* __restrict__ EF, const ushort* __restrict__ W1G,
    const ushort* __restrict__ B2G, const float* __restrict__ tail,
    ushort* __restrict__ E2)
{
    __shared__ __align__(16) char xt[4 * 16 * 528];  // 33792 B, per-wave tiles
    int tid = threadIdx.x;
    int wv = tid >> 6, lane = tid & 63;
    int q = lane >> 4, n = lane & 15;
    char* myx = xt + wv * (16 * 528);

    int bi = blockIdx.x;            // b*512 + i
    int b = bi >> 9, i = bi & 511;
    size_t rowbase = (size_t)bi * 512;

    short8 w1f[16];
#pragma unroll
    for (int t = 0; t < 16; ++t)
        w1f[t] = *(const short8*)(W1G + (t * 64 + lane) * 8);
    short8 b2f[8];
#pragma unroll
    for (int kc = 0; kc < 8; ++kc)
        b2f[kc] = *(const short8*)(B2G + (kc * 64 + lane) * 8);

    float shv = tail[n];
    float bbv = tail[8 + n];
    const ushort ONE = 0x3F80;
    const float inv256 = 1.0f / 256.0f;

    for (int iter = 0; iter < 8; ++iter) {
        int jb = iter * 64 + wv * 16;
        const float* efp = EF + (rowbase + jb + n) * 5;
        float ev[5];
#pragma unroll
        for (int e = 0; e < 5; ++e) ev[e] = efp[e];

        ushort hh[5], llo[5];
#pragma unroll
        for (int e = 0; e < 5; ++e) {
            ushort hi = f2bf(ev[e]);
            hh[e] = hi;
            llo[e] = f2bf(ev[e] - bf2f(hi));
        }
        // B operand: EFaug[k][pair], lane: pair=n, k=q*8+j
        short8 ef8;
        ef8[0] = (short)(q == 0 ? hh[0] : q == 1 ? hh[3] : q == 2 ? ONE : 0);
        ef8[1] = (short)(q == 0 ? hh[1] : q == 1 ? hh[4] : 0);
        ef8[2] = (short)(q == 0 ? hh[2] : q == 1 ? llo[0] : 0);
        ef8[3] = (short)(q == 0 ? hh[3] : q == 1 ? llo[1] : 0);
        ef8[4] = (short)(q == 0 ? hh[4] : q == 1 ? llo[2] : 0);
        ef8[5] = (short)(q == 0 ? hh[0] : q == 1 ? llo[3] : 0);
        ef8[6] = (short)(q == 0 ? hh[1] : q == 1 ? llo[4] : 0);
        ef8[7] = (short)(q == 0 ? hh[2] : q == 1 ? ONE : 0);

        float sumacc = 0.f, sqacc = 0.f;
        // Stage A: 16 d-tiles. D1[m=d_local][n'=pair]: lane holds pair=n,
        // d = t*16 + q*4 + r (r=0..3) -> 4 consecutive d.
#pragma unroll
        for (int t = 0; t < 16; ++t) {
            f32x4 z = {0.f, 0.f, 0.f, 0.f};
            f32x4 d1 = __builtin_amdgcn_mfma_f32_16x16x32_bf16(w1f[t], ef8, z, 0, 0, 0);
            float x0 = fmaxf(d1[0], 0.f);
            float x1 = fmaxf(d1[1], 0.f);
            float x2 = fmaxf(d1[2], 0.f);
            float x3 = fmaxf(d1[3], 0.f);
            sumacc += (x0 + x1) + (x2 + x3);
            sqacc = fmaf(x0, x0, sqacc);
            sqacc = fmaf(x1, x1, sqacc);
            sqacc = fmaf(x2, x2, sqacc);
            sqacc = fmaf(x3, x3, sqacc);
            uint2 pk;
            pk.x = (unsigned int)f2bf(x0) | ((unsigned int)f2bf(x1) << 16);
            pk.y = (unsigned int)f2bf(x2) | ((unsigned int)f2bf(x3) << 16);
            *(uint2*)(myx + n * 528 + t * 32 + q * 8) = pk;
        }
        // per-pair totals (pair = n): combine the 4 quarter-partials
        sumacc += __shfl_xor(sumacc, 16);
        sumacc += __shfl_xor(sumacc, 32);
        sqacc += __shfl_xor(sqacc, 16);
        sqacc += __shfl_xor(sqacc, 32);

        // Stage B: dots[pair][col]: A = X (m=pair=n, k=kc*32+q*8+j from LDS)
        f32x4 acc = {0.f, 0.f, 0.f, 0.f};
#pragma unroll
        for (int kc = 0; kc < 8; ++kc) {
            short8 a = *(const short8*)(myx + n * 528 + kc * 64 + q * 16);
            acc = __builtin_amdgcn_mfma_f32_16x16x32_bf16(a, b2f[kc], acc, 0, 0, 0);
        }

        // Epilogue. D2: col=n (head hi for n<8, lo for n>=8), row=pair=q*4+r.
        unsigned int lo32 = 0, hi32 = 0;
#pragma unroll
        for (int r = 0; r < 4; ++r) {
            int pairid = q * 4 + r;
            float sm = __shfl(sumacc, pairid);
            float sq = __shfl(sqacc, pairid);
            float dlo = __shfl(acc[r], (lane & 48) + n + 8);
            float dot = acc[r] + dlo;
            float mu = sm * inv256;
            float var = fmaf(-mu, mu, sq * inv256);
            float rs = rsqrtf(var + 1e-5f);
            float e2v = fmaf(dot - mu * shv, rs, bbv);
            ushort bv = f2bf(e2v);
            if (r < 2) lo32 |= ((unsigned int)bv) << (16 * r);
            else       hi32 |= ((unsigned int)bv) << (16 * (r - 2));
        }
        if (n < 8) {
            uint2 outv; outv.x = lo32; outv.y = hi32;
            size_t base = (((size_t)(b * NH + n) * L_SEQ + i) * L_SEQ) + jb + q * 4;
            *(uint2*)(E2 + base) = outv;
        }
    }
}

// ---------------------------------------------------------------------------
// attn: per block = (b,h, 16 query rows); per wave = 4 rows.
// ---------------------------------------------------------------------------
__global__ __launch_bounds__(256) void attn_kernel(
    const float* __restrict__ Q, const float* __restrict__ Kt,
    const float* __restrict__ V, const ushort* __restrict__ E2,
    const int* __restrict__ MSK, float* __restrict__ Y)
{
    __shared__ float pbuf[4][4][520];
    __shared__ float qs[16][33];
    int bh = blockIdx.x;
    int b = bh >> 3, h = bh & 7;
    int tid = threadIdx.x;
    int wv = __builtin_amdgcn_readfirstlane(tid >> 6);
    int lane = tid & 63;
    int i0 = blockIdx.y * 16;
    int i = i0 + wv * 4;

    if (tid < 128) {
        int r = tid >> 3;
        int c = (tid & 7) * 4;
        float4 qv = *(const float4*)(Q + ((size_t)(b * L_SEQ + i0 + r)) * 256 + h * HD + c);
        qs[r][c + 0] = qv.x; qs[r][c + 1] = qv.y;
        qs[r][c + 2] = qv.z; qs[r][c + 3] = qv.w;
    }
    __syncthreads();

    const float* Ktb = Kt + (size_t)bh * (HD * L_SEQ);
    const float* Vb = V + (size_t)b * L_SEQ * D_EMB + h * HD;

    float s[4][8];
#pragma unroll
    for (int r = 0; r < 4; ++r)
#pragma unroll
        for (int t = 0; t < 8; ++t) s[r][t] = 0.f;

#pragma unroll 2
    for (int d = 0; d < HD; ++d) {
        float q0 = qs[wv * 4 + 0][d];
        float q1 = qs[wv * 4 + 1][d];
        float q2 = qs[wv * 4 + 2][d];
        float q3 = qs[wv * 4 + 3][d];
        const float* kp = Ktb + (size_t)d * L_SEQ + lane;
#pragma unroll
        for (int t = 0; t < 8; ++t) {
            float kv = kp[t << 6];
            s[0][t] = fmaf(q0, kv, s[0][t]);
            s[1][t] = fmaf(q1, kv, s[1][t]);
            s[2][t] = fmaf(q2, kv, s[2][t]);
            s[3][t] = fmaf(q3, kv, s[3][t]);
        }
    }

    const float scl = 0.17677669529663687f;
    size_t erow = ((size_t)bh * L_SEQ + i) * L_SEQ;
    size_t mrow = ((size_t)b * L_SEQ + i) * L_SEQ;

#pragma unroll
    for (int r = 0; r < 4; ++r) {
        float m = -1e30f;
#pragma unroll
        for (int t = 0; t < 8; ++t) {
            int j = lane + (t << 6);
            float e = bf2f(E2[erow + (size_t)r * L_SEQ + j]);
            int mk = MSK[mrow + (size_t)r * L_SEQ + j];
            float sv = (mk != 0) ? fmaf(s[r][t], scl, e) : -1e30f;
            s[r][t] = sv;
            m = fmaxf(m, sv);
        }
#pragma unroll
        for (int o = 32; o > 0; o >>= 1) m = fmaxf(m, __shfl_xor(m, o));
        float ssum = 0.f;
#pragma unroll
        for (int t = 0; t < 8; ++t) {
            float p = __expf(s[r][t] - m);
            s[r][t] = p;
            ssum += p;
        }
#pragma unroll
        for (int o = 32; o > 0; o >>= 1) ssum += __shfl_xor(ssum, o);
        float inv = 1.0f / ssum;
#pragma unroll
        for (int t = 0; t < 8; ++t) pbuf[wv][r][lane + (t << 6)] = s[r][t] * inv;
    }
    __syncthreads();

    int r2 = lane >> 4;
    int dd = (lane & 15) << 1;
    float yx = 0.f, yy = 0.f;
#pragma unroll 4
    for (int j = 0; j < L_SEQ; j += 4) {
        float4 p4 = *(const float4*)&pbuf[wv][r2][j];
        const float* vp = Vb + (size_t)j * D_EMB + dd;
        float2 v0 = *(const float2*)(vp);
        float2 v1 = *(const float2*)(vp + D_EMB);
        float2 v2 = *(const float2*)(vp + 2 * D_EMB);
        float2 v3 = *(const float2*)(vp + 3 * D_EMB);
        yx = fmaf(p4.x, v0.x, fmaf(p4.y, v1.x, fmaf(p4.z, v2.x, fmaf(p4.w, v3.x, yx))));
        yy = fmaf(p4.x, v0.y, fmaf(p4.y, v1.y, fmaf(p4.z, v2.y, fmaf(p4.w, v3.y, yy))));
    }
    float2 out = make_float2(yx, yy);
    *(float2*)(Y + ((size_t)b * L_SEQ + i + r2) * D_EMB + h * HD + dd) = out;
}

// ---------------------------------------------------------------------------
extern "C" void kernel_launch(void* const* d_in, const int* in_sizes, int n_in,
                              void* d_out, int out_size, void* d_ws, size_t ws_size,
                              hipStream_t stream)
{
    const float* key   = (const float*)d_in[0];
    const float* value = (const float*)d_in[1];
    const float* query = (const float*)d_in[2];
    const int*   msk   = (const int*)d_in[3];
    const float* ef    = (const float*)d_in[4];
    const float* Wk  = (const float*)d_in[5];  const float* bk  = (const float*)d_in[6];
    const float* Wq  = (const float*)d_in[7];  const float* bq  = (const float*)d_in[8];
    const float* Wv  = (const float*)d_in[9];  const float* bv  = (const float*)d_in[10];
    const float* Wp  = (const float*)d_in[11]; const float* bp  = (const float*)d_in[12];
    const float* We1 = (const float*)d_in[13]; const float* be1 = (const float*)d_in[14];
    const float* lng = (const float*)d_in[15]; const float* lnb = (const float*)d_in[16];
    const float* We2 = (const float*)d_in[17]; const float* be2 = (const float*)d_in[18];

    const int MTOK = 4 * L_SEQ;          // 2048 rows
    const int NELT = MTOK * D_EMB;       // 524288

    float* ws    = (float*)d_ws;
    float* Qw    = ws;
    float* Kw    = Qw + NELT;
    float* Vw    = Kw + NELT;
    float* Yw    = Vw + NELT;
    float* Ktw   = Yw + NELT;
    ushort* W1G  = (ushort*)(Ktw + NELT);   // 8192 bf16
    ushort* B2G  = W1G + 8192;              // 4096 bf16
    float* tail  = (float*)(B2G + 4096);    // 32 floats
    ushort* E2   = (ushort*)(tail + 32);    // 8388608 bf16 (~16.8 MB)

    hipLaunchKernelGGL(prep_kernel, dim3(1), dim3(256), 0, stream,
                       We1, be1, lng, lnb, We2, be2, W1G, B2G, tail);
    hipLaunchKernelGGL(gemm256, dim3(32, 4, 3), dim3(256), 0, stream,
                       query, Wq, bq, Qw,
                       key,   Wk, bk, Kw,
                       value, Wv, bv, Vw);
    hipLaunchKernelGGL(transpose_k, dim3(32, 4), dim3(256), 0, stream,
                       Kw, Ktw);
    hipLaunchKernelGGL(edge_bias_mfma, dim3(2048), dim3(256), 0, stream,
                       ef, W1G, B2G, tail, E2);
    hipLaunchKernelGGL(attn_kernel, dim3(32, 32), dim3(256), 0, stream,
                       Qw, Ktw, Vw, E2, msk, Yw);
    hipLaunchKernelGGL(gemm256, dim3(32, 4, 1), dim3(256), 0, stream,
                       Yw, Wp, bp, (float*)d_out,
                       Yw, Wp, bp, (float*)d_out,
                       Yw, Wp, bp, (float*)d_out);
}

// Round 4
// 260.987 us; speedup vs baseline: 1.3298x; 1.1838x over previous
//
#include <hip/hip_runtime.h>
#include <hip/hip_bf16.h>

#define L_SEQ 512
#define D_EMB 256
#define NH 8
#define HD 32
#define LL (L_SEQ * L_SEQ)   // 262144

typedef __attribute__((ext_vector_type(8))) short short8;
typedef __attribute__((ext_vector_type(4))) float f32x4;
typedef unsigned short ushort;

__device__ __forceinline__ float bf2f(ushort u) {
    unsigned int x = ((unsigned int)u) << 16;
    float f;
    __builtin_memcpy(&f, &x, 4);
    return f;
}
__device__ __forceinline__ ushort f2bf(float x) {
    __hip_bfloat16 h = __float2bfloat16(x);
    ushort u;
    __builtin_memcpy(&u, &h, 2);
    return u;
}

// ---------------------------------------------------------------------------
// prep: build MFMA fragment tables for the edge kernel + LN-fold tails.
// ---------------------------------------------------------------------------
__global__ __launch_bounds__(256) void prep_kernel(
    const float* __restrict__ We1, const float* __restrict__ be1,
    const float* __restrict__ g,   const float* __restrict__ bta,
    const float* __restrict__ We2, const float* __restrict__ be2,
    ushort* __restrict__ W1G, ushort* __restrict__ B2G, float* __restrict__ tail)
{
    int t = threadIdx.x;  // 0..255
    __shared__ float red[16][256];
    float gd = g[t], bd = bta[t];
#pragma unroll
    for (int h = 0; h < 8; ++h) {
        float w2 = We2[t * 8 + h];
        red[h][t] = gd * w2;
        red[8 + h][t] = bd * w2;
    }
    __syncthreads();
    for (int off = 128; off > 0; off >>= 1) {
        if (t < off) {
#pragma unroll
            for (int row = 0; row < 16; ++row) red[row][t] += red[row][t + off];
        }
        __syncthreads();
    }
    if (t < 8) {
        tail[t] = red[t][0];
        tail[8 + t] = red[8 + t][0] + be2[t];
    }
    if (t >= 16 && t < 32) tail[t] = 0.f;

    // W1G: 8192 entries
    for (int idx = t; idx < 8192; idx += 256) {
        int j = idx & 7, lane = (idx >> 3) & 63, tile = idx >> 9;
        int m = lane & 15, q = lane >> 4;
        int k = q * 8 + j;
        int d = tile * 16 + m;
        float v = 0.f;
        bool lo = false;
        if (k < 5)        v = We1[k * 256 + d];
        else if (k < 10)  { v = We1[(k - 5) * 256 + d]; lo = true; }
        else if (k < 15)  v = We1[(k - 10) * 256 + d];
        else if (k == 15) v = be1[d];
        else if (k == 16) { v = be1[d]; lo = true; }
        ushort hi = f2bf(v);
        W1G[idx] = lo ? f2bf(v - bf2f(hi)) : hi;
    }
    // B2G: 4096 entries
    for (int idx = t; idx < 4096; idx += 256) {
        int j = idx & 7, lane = (idx >> 3) & 63, kc = idx >> 9;
        int n = lane & 15, q = lane >> 4;
        int d = kc * 32 + q * 8 + j;
        float w = g[d] * We2[d * 8 + (n & 7)];
        ushort hi = f2bf(w);
        B2G[idx] = (n < 8) ? hi : f2bf(w - bf2f(hi));
    }
}

// ---------------------------------------------------------------------------
// gemm256: C[2048,256] = A[2048,256] @ W[256,256] + bias  (fp32, tiled)
// ---------------------------------------------------------------------------
__global__ __launch_bounds__(256) void gemm256(
    const float* __restrict__ A0, const float* __restrict__ W0,
    const float* __restrict__ b0, float* __restrict__ C0,
    const float* __restrict__ A1, const float* __restrict__ W1,
    const float* __restrict__ b1, float* __restrict__ C1,
    const float* __restrict__ A2, const float* __restrict__ W2,
    const float* __restrict__ b2, float* __restrict__ C2)
{
    const float* A; const float* W; const float* bias; float* C;
    if (blockIdx.z == 0)      { A = A0; W = W0; bias = b0; C = C0; }
    else if (blockIdx.z == 1) { A = A1; W = W1; bias = b1; C = C1; }
    else                      { A = A2; W = W2; bias = b2; C = C2; }

    __shared__ float As[16][68];
    __shared__ float Ws[16][64];

    int tid = threadIdx.x;
    int bm = blockIdx.x * 64, bn = blockIdx.y * 64;
    int tm = (tid >> 4) * 4, tn = (tid & 15) * 4;
    int lr = tid >> 2, lk = (tid & 3) * 4;
    int wr = tid >> 4, wn = (tid & 15) * 4;

    float acc[4][4] = {};
    for (int k0 = 0; k0 < 256; k0 += 16) {
        float4 a4 = *(const float4*)(A + (size_t)(bm + lr) * 256 + k0 + lk);
        As[lk + 0][lr] = a4.x; As[lk + 1][lr] = a4.y;
        As[lk + 2][lr] = a4.z; As[lk + 3][lr] = a4.w;
        *(float4*)&Ws[wr][wn] = *(const float4*)(W + (size_t)(k0 + wr) * 256 + bn + wn);
        __syncthreads();
#pragma unroll
        for (int k = 0; k < 16; ++k) {
            float4 av = *(const float4*)&As[k][tm];
            float4 bv = *(const float4*)&Ws[k][tn];
            acc[0][0] = fmaf(av.x, bv.x, acc[0][0]);
            acc[0][1] = fmaf(av.x, bv.y, acc[0][1]);
            acc[0][2] = fmaf(av.x, bv.z, acc[0][2]);
            acc[0][3] = fmaf(av.x, bv.w, acc[0][3]);
            acc[1][0] = fmaf(av.y, bv.x, acc[1][0]);
            acc[1][1] = fmaf(av.y, bv.y, acc[1][1]);
            acc[1][2] = fmaf(av.y, bv.z, acc[1][2]);
            acc[1][3] = fmaf(av.y, bv.w, acc[1][3]);
            acc[2][0] = fmaf(av.z, bv.x, acc[2][0]);
            acc[2][1] = fmaf(av.z, bv.y, acc[2][1]);
            acc[2][2] = fmaf(av.z, bv.z, acc[2][2]);
            acc[2][3] = fmaf(av.z, bv.w, acc[2][3]);
            acc[3][0] = fmaf(av.w, bv.x, acc[3][0]);
            acc[3][1] = fmaf(av.w, bv.y, acc[3][1]);
            acc[3][2] = fmaf(av.w, bv.z, acc[3][2]);
            acc[3][3] = fmaf(av.w, bv.w, acc[3][3]);
        }
        __syncthreads();
    }
    float4 bia = *(const float4*)(bias + bn + tn);
#pragma unroll
    for (int r = 0; r < 4; ++r) {
        float4 o;
        o.x = acc[r][0] + bia.x; o.y = acc[r][1] + bia.y;
        o.z = acc[r][2] + bia.z; o.w = acc[r][3] + bia.w;
        *(float4*)(C + (size_t)(bm + tm + r) * 256 + bn + tn) = o;
    }
}

// ---------------------------------------------------------------------------
// transpose_k: Kw [B*L, 256] -> Kt [B, H, HD, L]
// ---------------------------------------------------------------------------
__global__ __launch_bounds__(256) void transpose_k(
    const float* __restrict__ Kw, float* __restrict__ Kt)
{
    __shared__ float tile[128][33];
    int bh = blockIdx.x;
    int b = bh >> 3, h = bh & 7;
    int l0 = blockIdx.y * 128;
    int tid = threadIdx.x;

    int tr = tid >> 3;
    int tc = (tid & 7) * 4;
#pragma unroll
    for (int p = 0; p < 4; ++p) {
        int ll = p * 32 + tr;
        float4 v = *(const float4*)(Kw + ((size_t)(b * L_SEQ + l0 + ll)) * 256 + h * HD + tc);
        tile[ll][tc + 0] = v.x; tile[ll][tc + 1] = v.y;
        tile[ll][tc + 2] = v.z; tile[ll][tc + 3] = v.w;
    }
    __syncthreads();

    float* out = Kt + (size_t)bh * (HD * L_SEQ);
#pragma unroll
    for (int it = 0; it < 16; ++it) {
        int flat = it * 256 + tid;
        int d = flat >> 7;
        int l = flat & 127;
        out[(size_t)d * L_SEQ + l0 + l] = tile[l][d];
    }
}

// ---------------------------------------------------------------------------
// edge_bias_mfma: unchanged from round 3 (fell out of top-5).
// ---------------------------------------------------------------------------
__global__ __launch_bounds__(256) void edge_bias_mfma(
    const float* __restrict__ EF, const ushort* __restrict__ W1G,
    const ushort* __restrict__ B2G, const float* __restrict__ tail,
    ushort* __restrict__ E2)
{
    __shared__ __align__(16) char xt[4 * 16 * 528];  // 33792 B, per-wave tiles
    int tid = threadIdx.x;
    int wv = tid >> 6, lane = tid & 63;
    int q = lane >> 4, n = lane & 15;
    char* myx = xt + wv * (16 * 528);

    int bi = blockIdx.x;            // b*512 + i
    int b = bi >> 9, i = bi & 511;
    size_t rowbase = (size_t)bi * 512;

    short8 w1f[16];
#pragma unroll
    for (int t = 0; t < 16; ++t)
        w1f[t] = *(const short8*)(W1G + (t * 64 + lane) * 8);
    short8 b2f[8];
#pragma unroll
    for (int kc = 0; kc < 8; ++kc)
        b2f[kc] = *(const short8*)(B2G + (kc * 64 + lane) * 8);

    float shv = tail[n];
    float bbv = tail[8 + n];
    const ushort ONE = 0x3F80;
    const float inv256 = 1.0f / 256.0f;

    for (int iter = 0; iter < 8; ++iter) {
        int jb = iter * 64 + wv * 16;
        const float* efp = EF + (rowbase + jb + n) * 5;
        float ev[5];
#pragma unroll
        for (int e = 0; e < 5; ++e) ev[e] = efp[e];

        ushort hh[5], llo[5];
#pragma unroll
        for (int e = 0; e < 5; ++e) {
            ushort hi = f2bf(ev[e]);
            hh[e] = hi;
            llo[e] = f2bf(ev[e] - bf2f(hi));
        }
        short8 ef8;
        ef8[0] = (short)(q == 0 ? hh[0] : q == 1 ? hh[3] : q == 2 ? ONE : 0);
        ef8[1] = (short)(q == 0 ? hh[1] : q == 1 ? hh[4] : 0);
        ef8[2] = (short)(q == 0 ? hh[2] : q == 1 ? llo[0] : 0);
        ef8[3] = (short)(q == 0 ? hh[3] : q == 1 ? llo[1] : 0);
        ef8[4] = (short)(q == 0 ? hh[4] : q == 1 ? llo[2] : 0);
        ef8[5] = (short)(q == 0 ? hh[0] : q == 1 ? llo[3] : 0);
        ef8[6] = (short)(q == 0 ? hh[1] : q == 1 ? llo[4] : 0);
        ef8[7] = (short)(q == 0 ? hh[2] : q == 1 ? ONE : 0);

        float sumacc = 0.f, sqacc = 0.f;
#pragma unroll
        for (int t = 0; t < 16; ++t) {
            f32x4 z = {0.f, 0.f, 0.f, 0.f};
            f32x4 d1 = __builtin_amdgcn_mfma_f32_16x16x32_bf16(w1f[t], ef8, z, 0, 0, 0);
            float x0 = fmaxf(d1[0], 0.f);
            float x1 = fmaxf(d1[1], 0.f);
            float x2 = fmaxf(d1[2], 0.f);
            float x3 = fmaxf(d1[3], 0.f);
            sumacc += (x0 + x1) + (x2 + x3);
            sqacc = fmaf(x0, x0, sqacc);
            sqacc = fmaf(x1, x1, sqacc);
            sqacc = fmaf(x2, x2, sqacc);
            sqacc = fmaf(x3, x3, sqacc);
            uint2 pk;
            pk.x = (unsigned int)f2bf(x0) | ((unsigned int)f2bf(x1) << 16);
            pk.y = (unsigned int)f2bf(x2) | ((unsigned int)f2bf(x3) << 16);
            *(uint2*)(myx + n * 528 + t * 32 + q * 8) = pk;
        }
        sumacc += __shfl_xor(sumacc, 16);
        sumacc += __shfl_xor(sumacc, 32);
        sqacc += __shfl_xor(sqacc, 16);
        sqacc += __shfl_xor(sqacc, 32);

        f32x4 acc = {0.f, 0.f, 0.f, 0.f};
#pragma unroll
        for (int kc = 0; kc < 8; ++kc) {
            short8 a = *(const short8*)(myx + n * 528 + kc * 64 + q * 16);
            acc = __builtin_amdgcn_mfma_f32_16x16x32_bf16(a, b2f[kc], acc, 0, 0, 0);
        }

        unsigned int lo32 = 0, hi32 = 0;
#pragma unroll
        for (int r = 0; r < 4; ++r) {
            int pairid = q * 4 + r;
            float sm = __shfl(sumacc, pairid);
            float sq = __shfl(sqacc, pairid);
            float dlo = __shfl(acc[r], (lane & 48) + n + 8);
            float dot = acc[r] + dlo;
            float mu = sm * inv256;
            float var = fmaf(-mu, mu, sq * inv256);
            float rs = rsqrtf(var + 1e-5f);
            float e2v = fmaf(dot - mu * shv, rs, bbv);
            ushort bv = f2bf(e2v);
            if (r < 2) lo32 |= ((unsigned int)bv) << (16 * r);
            else       hi32 |= ((unsigned int)bv) << (16 * (r - 2));
        }
        if (n < 8) {
            uint2 outv; outv.x = lo32; outv.y = hi32;
            size_t base = (((size_t)(b * NH + n) * L_SEQ + i) * L_SEQ) + jb + q * 4;
            *(uint2*)(E2 + base) = outv;
        }
    }
}

// ---------------------------------------------------------------------------
// attn: per block = (b,h, 16 query rows); per wave = 4 rows.
// Two-pass LDS staging: K chunks [32][128] for QK^T, then V chunks [128][32]
// for PV through the SAME 16 KB stage buffer. E2/MSK prefetched to registers
// at kernel start (consumed only after QK^T -> latency fully hidden).
// j-mapping: j = c*128 + 2*lane + u  (score reg s[r][c*2+u]).
// PV lane map: dg=lane>>3 (4-d group), js=lane&7 (j slot) -> dedup b128 V
// reads; 3-step shfl reduce over js at the end.
// ---------------------------------------------------------------------------
__global__ __launch_bounds__(256, 3) void attn_kernel(
    const float* __restrict__ Q, const float* __restrict__ Kt,
    const float* __restrict__ V, const ushort* __restrict__ E2,
    const int* __restrict__ MSK, float* __restrict__ Y)
{
    __shared__ float stage[4096];       // 16 KB: K chunk [32][128] / V chunk [128][32]
    __shared__ float pbuf[4][4][520];   // per-wave p rows (fp32)
    __shared__ float qs_t[32][16];      // q transposed: [d][row]

    int bh = blockIdx.x;
    int b = bh >> 3, h = bh & 7;
    int tid = threadIdx.x;
    int wv = tid >> 6, lane = tid & 63;
    int i0 = blockIdx.y * 16;
    int i = i0 + wv * 4;

    const float* Ktb = Kt + (size_t)bh * (HD * L_SEQ);
    const float* Vb  = V + (size_t)b * L_SEQ * D_EMB + h * HD;

    size_t erow = ((size_t)bh * L_SEQ + i) * L_SEQ;
    size_t mrow = ((size_t)b * L_SEQ + i) * L_SEQ;

    // ---- prefetch E2 + mask for all 4 rows x 4 chunks (hidden behind QK^T)
    unsigned int e2p[4][4];
    int2 mkp[4][4];
#pragma unroll
    for (int r = 0; r < 4; ++r)
#pragma unroll
        for (int c = 0; c < 4; ++c) {
            int j = c * 128 + 2 * lane;
            e2p[r][c] = *(const unsigned int*)(E2 + erow + (size_t)r * L_SEQ + j);
            mkp[r][c] = *(const int2*)(MSK + mrow + (size_t)r * L_SEQ + j);
        }

    // ---- stage Q transposed (once)
    if (tid < 128) {
        int r = tid >> 3, c4 = (tid & 7) * 4;
        float4 qv = *(const float4*)(Q + ((size_t)(b * L_SEQ + i0 + r)) * 256 + h * HD + c4);
        qs_t[c4 + 0][r] = qv.x; qs_t[c4 + 1][r] = qv.y;
        qs_t[c4 + 2][r] = qv.z; qs_t[c4 + 3][r] = qv.w;
    }

    float s[4][8];
#pragma unroll
    for (int r = 0; r < 4; ++r)
#pragma unroll
        for (int t = 0; t < 8; ++t) s[r][t] = 0.f;

    // ---- phase 1: QK^T over 4 K-chunks
    for (int c = 0; c < 4; ++c) {
        if (c) __syncthreads();   // prior chunk's reads done before overwrite
        {
            int d0 = tid >> 5, jj = (tid & 31) * 4;
#pragma unroll
            for (int p = 0; p < 4; ++p) {
                int d = p * 8 + d0;
                float4 kv = *(const float4*)(Ktb + (size_t)d * L_SEQ + c * 128 + jj);
                *(float4*)&stage[d * 128 + jj] = kv;
            }
        }
        __syncthreads();
        int c2 = c * 2;
#pragma unroll 8
        for (int d = 0; d < HD; ++d) {
            float4 q4 = *(const float4*)&qs_t[d][wv * 4];
            float2 kv = *(const float2*)&stage[d * 128 + 2 * lane];
            s[0][c2]     = fmaf(q4.x, kv.x, s[0][c2]);
            s[0][c2 + 1] = fmaf(q4.x, kv.y, s[0][c2 + 1]);
            s[1][c2]     = fmaf(q4.y, kv.x, s[1][c2]);
            s[1][c2 + 1] = fmaf(q4.y, kv.y, s[1][c2 + 1]);
            s[2][c2]     = fmaf(q4.z, kv.x, s[2][c2]);
            s[2][c2 + 1] = fmaf(q4.z, kv.y, s[2][c2 + 1]);
            s[3][c2]     = fmaf(q4.w, kv.x, s[3][c2]);
            s[3][c2 + 1] = fmaf(q4.w, kv.y, s[3][c2 + 1]);
        }
    }

    // ---- softmax (registers + wave shuffles; p -> own wave's pbuf rows)
    const float scl = 0.17677669529663687f;  // 1/sqrt(32)
#pragma unroll
    for (int r = 0; r < 4; ++r) {
        float sv[8];
        float m = -3.0e38f;
#pragma unroll
        for (int idx = 0; idx < 8; ++idx) {
            int c = idx >> 1, u = idx & 1;
            unsigned int pk = e2p[r][c];
            float e = bf2f((ushort)(u ? (pk >> 16) : (pk & 0xffff)));
            int mk = u ? mkp[r][c].y : mkp[r][c].x;
            float v = (mk != 0) ? fmaf(s[r][idx], scl, e) : -1e30f;
            sv[idx] = v;
            m = fmaxf(m, v);
        }
#pragma unroll
        for (int o = 32; o > 0; o >>= 1) m = fmaxf(m, __shfl_xor(m, o));
        float ssum = 0.f;
#pragma unroll
        for (int idx = 0; idx < 8; ++idx) {
            float p = __expf(sv[idx] - m);
            sv[idx] = p;
            ssum += p;
        }
#pragma unroll
        for (int o = 32; o > 0; o >>= 1) ssum += __shfl_xor(ssum, o);
        float inv = 1.0f / ssum;
#pragma unroll
        for (int c = 0; c < 4; ++c) {
            float2 w;
            w.x = sv[c * 2] * inv;
            w.y = sv[c * 2 + 1] * inv;
            *(float2*)&pbuf[wv][r][c * 128 + 2 * lane] = w;
        }
    }

    // ---- phase 2: PV over 4 V-chunks (same stage buffer)
    int dg = lane >> 3, js = lane & 7;
    float4 acc[4];
#pragma unroll
    for (int r = 0; r < 4; ++r) { acc[r].x = 0.f; acc[r].y = 0.f; acc[r].z = 0.f; acc[r].w = 0.f; }

    for (int c = 0; c < 4; ++c) {
        __syncthreads();          // prior stage reads (K chunk 3 / V chunk c-1) done
        {
            int j0 = tid >> 3, dd = (tid & 7) * 4;
#pragma unroll
            for (int p = 0; p < 4; ++p) {
                int j = p * 32 + j0;
                float4 vv = *(const float4*)(Vb + (size_t)(c * 128 + j) * D_EMB + dd);
                *(float4*)&stage[j * 32 + dd] = vv;
            }
        }
        __syncthreads();
#pragma unroll
        for (int jb = 0; jb < 16; ++jb) {
            int jj = jb * 8 + js;
            float4 v4 = *(const float4*)&stage[jj * 32 + dg * 4];
#pragma unroll
            for (int r = 0; r < 4; ++r) {
                float p = pbuf[wv][r][c * 128 + jj];
                acc[r].x = fmaf(p, v4.x, acc[r].x);
                acc[r].y = fmaf(p, v4.y, acc[r].y);
                acc[r].z = fmaf(p, v4.z, acc[r].z);
                acc[r].w = fmaf(p, v4.w, acc[r].w);
            }
        }
    }

    // ---- reduce over the 8 j-slots
#pragma unroll
    for (int off = 1; off < 8; off <<= 1) {
#pragma unroll
        for (int r = 0; r < 4; ++r) {
            acc[r].x += __shfl_xor(acc[r].x, off);
            acc[r].y += __shfl_xor(acc[r].y, off);
            acc[r].z += __shfl_xor(acc[r].z, off);
            acc[r].w += __shfl_xor(acc[r].w, off);
        }
    }
    if (js == 0) {
#pragma unroll
        for (int r = 0; r < 4; ++r)
            *(float4*)(Y + ((size_t)(b * L_SEQ + i + r)) * 256 + h * HD + dg * 4) = acc[r];
    }
}

// ---------------------------------------------------------------------------
extern "C" void kernel_launch(void* const* d_in, const int* in_sizes, int n_in,
                              void* d_out, int out_size, void* d_ws, size_t ws_size,
                              hipStream_t stream)
{
    const float* key   = (const float*)d_in[0];
    const float* value = (const float*)d_in[1];
    const float* query = (const float*)d_in[2];
    const int*   msk   = (const int*)d_in[3];
    const float* ef    = (const float*)d_in[4];
    const float* Wk  = (const float*)d_in[5];  const float* bk  = (const float*)d_in[6];
    const float* Wq  = (const float*)d_in[7];  const float* bq  = (const float*)d_in[8];
    const float* Wv  = (const float*)d_in[9];  const float* bv  = (const float*)d_in[10];
    const float* Wp  = (const float*)d_in[11]; const float* bp  = (const float*)d_in[12];
    const float* We1 = (const float*)d_in[13]; const float* be1 = (const float*)d_in[14];
    const float* lng = (const float*)d_in[15]; const float* lnb = (const float*)d_in[16];
    const float* We2 = (const float*)d_in[17]; const float* be2 = (const float*)d_in[18];

    const int MTOK = 4 * L_SEQ;          // 2048 rows
    const int NELT = MTOK * D_EMB;       // 524288

    float* ws    = (float*)d_ws;
    float* Qw    = ws;
    float* Kw    = Qw + NELT;
    float* Vw    = Kw + NELT;
    float* Yw    = Vw + NELT;
    float* Ktw   = Yw + NELT;
    ushort* W1G  = (ushort*)(Ktw + NELT);   // 8192 bf16
    ushort* B2G  = W1G + 8192;              // 4096 bf16
    float* tail  = (float*)(B2G + 4096);    // 32 floats
    ushort* E2   = (ushort*)(tail + 32);    // 8388608 bf16 (~16.8 MB)

    hipLaunchKernelGGL(prep_kernel, dim3(1), dim3(256), 0, stream,
                       We1, be1, lng, lnb, We2, be2, W1G, B2G, tail);
    hipLaunchKernelGGL(gemm256, dim3(32, 4, 3), dim3(256), 0, stream,
                       query, Wq, bq, Qw,
                       key,   Wk, bk, Kw,
                       value, Wv, bv, Vw);
    hipLaunchKernelGGL(transpose_k, dim3(32, 4), dim3(256), 0, stream,
                       Kw, Ktw);
    hipLaunchKernelGGL(edge_bias_mfma, dim3(2048), dim3(256), 0, stream,
                       ef, W1G, B2G, tail, E2);
    hipLaunchKernelGGL(attn_kernel, dim3(32, 32), dim3(256), 0, stream,
                       Qw, Ktw, Vw, E2, msk, Yw);
    hipLaunchKernelGGL(gemm256, dim3(32, 4, 1), dim3(256), 0, stream,
                       Yw, Wp, bp, (float*)d_out,
                       Yw, Wp, bp, (float*)d_out,
                       Yw, Wp, bp, (float*)d_out);
}

// Round 5
// 255.927 us; speedup vs baseline: 1.3561x; 1.0198x over previous
//
#include <hip/hip_runtime.h>
#include <hip/hip_bf16.h>

#define L_SEQ 512
#define D_EMB 256
#define NH 8
#define HD 32
#define LL (L_SEQ * L_SEQ)   // 262144

typedef __attribute__((ext_vector_type(8))) short short8;
typedef __attribute__((ext_vector_type(4))) float f32x4;
typedef unsigned short ushort;

__device__ __forceinline__ float bf2f(ushort u) {
    unsigned int x = ((unsigned int)u) << 16;
    float f;
    __builtin_memcpy(&f, &x, 4);
    return f;
}
__device__ __forceinline__ ushort f2bf(float x) {   // RNE (host-quality), prep only
    __hip_bfloat16 h = __float2bfloat16(x);
    ushort u;
    __builtin_memcpy(&u, &h, 2);
    return u;
}
__device__ __forceinline__ unsigned int fbits(float x) {
    unsigned int u;
    __builtin_memcpy(&u, &x, 4);
    return u;
}
// pack bf16(a) | bf16(b)<<16, nearest-ties-away rounding, 3 VALU ops
__device__ __forceinline__ unsigned int pack_bf16rnd(float a, float b) {
    return __builtin_amdgcn_perm(fbits(b) + 0x8000u, fbits(a) + 0x8000u, 0x07060302u);
}

// ---------------------------------------------------------------------------
// prep: build MFMA fragment tables for the edge kernel + LN-fold tails.
// W1G (stage-A A-op, 16x64x8): K slots: 0-4 hi(We1), 5-9 lo(We1), 10-14 hi(We1),
//   15 hi(be1), 16 lo(be1), rest 0  (EF hi/lo split -> fp32-accurate X).
// B2G (stage-B B-op, 8x64x8): col n<8 = hi(g*We2[:,n]); col 8 = 1.0 (gives
//   sum(x) via the same MFMA); cols 9-15 = 0.
// tail[0..7]=sh[h]; tail[8..15]=bb[h]
// ---------------------------------------------------------------------------
__global__ __launch_bounds__(256) void prep_kernel(
    const float* __restrict__ We1, const float* __restrict__ be1,
    const float* __restrict__ g,   const float* __restrict__ bta,
    const float* __restrict__ We2, const float* __restrict__ be2,
    ushort* __restrict__ W1G, ushort* __restrict__ B2G, float* __restrict__ tail)
{
    int t = threadIdx.x;  // 0..255
    __shared__ float red[16][256];
    float gd = g[t], bd = bta[t];
#pragma unroll
    for (int h = 0; h < 8; ++h) {
        float w2 = We2[t * 8 + h];
        red[h][t] = gd * w2;
        red[8 + h][t] = bd * w2;
    }
    __syncthreads();
    for (int off = 128; off > 0; off >>= 1) {
        if (t < off) {
#pragma unroll
            for (int row = 0; row < 16; ++row) red[row][t] += red[row][t + off];
        }
        __syncthreads();
    }
    if (t < 8) {
        tail[t] = red[t][0];
        tail[8 + t] = red[8 + t][0] + be2[t];
    }
    if (t >= 16 && t < 32) tail[t] = 0.f;

    // W1G: 8192 entries
    for (int idx = t; idx < 8192; idx += 256) {
        int j = idx & 7, lane = (idx >> 3) & 63, tile = idx >> 9;
        int m = lane & 15, q = lane >> 4;
        int k = q * 8 + j;
        int d = tile * 16 + m;
        float v = 0.f;
        bool lo = false;
        if (k < 5)        v = We1[k * 256 + d];
        else if (k < 10)  { v = We1[(k - 5) * 256 + d]; lo = true; }
        else if (k < 15)  v = We1[(k - 10) * 256 + d];
        else if (k == 15) v = be1[d];
        else if (k == 16) { v = be1[d]; lo = true; }
        ushort hi = f2bf(v);
        W1G[idx] = lo ? f2bf(v - bf2f(hi)) : hi;
    }
    // B2G: 4096 entries: cols 0-7 hi(g*We2), col 8 ones, 9-15 zero
    for (int idx = t; idx < 4096; idx += 256) {
        int j = idx & 7, lane = (idx >> 3) & 63, kc = idx >> 9;
        int n = lane & 15, q = lane >> 4;
        int d = kc * 32 + q * 8 + j;
        ushort out;
        if (n < 8)       out = f2bf(g[d] * We2[d * 8 + n]);
        else if (n == 8) out = 0x3F80;   // 1.0 bf16
        else             out = 0;
        B2G[idx] = out;
    }
}

// ---------------------------------------------------------------------------
// gemm256: C[2048,256] = A[2048,256] @ W[256,256] + bias  (fp32, tiled)
// ---------------------------------------------------------------------------
__global__ __launch_bounds__(256) void gemm256(
    const float* __restrict__ A0, const float* __restrict__ W0,
    const float* __restrict__ b0, float* __restrict__ C0,
    const float* __restrict__ A1, const float* __restrict__ W1,
    const float* __restrict__ b1, float* __restrict__ C1,
    const float* __restrict__ A2, const float* __restrict__ W2,
    const float* __restrict__ b2, float* __restrict__ C2)
{
    const float* A; const float* W; const float* bias; float* C;
    if (blockIdx.z == 0)      { A = A0; W = W0; bias = b0; C = C0; }
    else if (blockIdx.z == 1) { A = A1; W = W1; bias = b1; C = C1; }
    else                      { A = A2; W = W2; bias = b2; C = C2; }

    __shared__ float As[16][68];
    __shared__ float Ws[16][64];

    int tid = threadIdx.x;
    int bm = blockIdx.x * 64, bn = blockIdx.y * 64;
    int tm = (tid >> 4) * 4, tn = (tid & 15) * 4;
    int lr = tid >> 2, lk = (tid & 3) * 4;
    int wr = tid >> 4, wn = (tid & 15) * 4;

    float acc[4][4] = {};
    for (int k0 = 0; k0 < 256; k0 += 16) {
        float4 a4 = *(const float4*)(A + (size_t)(bm + lr) * 256 + k0 + lk);
        As[lk + 0][lr] = a4.x; As[lk + 1][lr] = a4.y;
        As[lk + 2][lr] = a4.z; As[lk + 3][lr] = a4.w;
        *(float4*)&Ws[wr][wn] = *(const float4*)(W + (size_t)(k0 + wr) * 256 + bn + wn);
        __syncthreads();
#pragma unroll
        for (int k = 0; k < 16; ++k) {
            float4 av = *(const float4*)&As[k][tm];
            float4 bv = *(const float4*)&Ws[k][tn];
            acc[0][0] = fmaf(av.x, bv.x, acc[0][0]);
            acc[0][1] = fmaf(av.x, bv.y, acc[0][1]);
            acc[0][2] = fmaf(av.x, bv.z, acc[0][2]);
            acc[0][3] = fmaf(av.x, bv.w, acc[0][3]);
            acc[1][0] = fmaf(av.y, bv.x, acc[1][0]);
            acc[1][1] = fmaf(av.y, bv.y, acc[1][1]);
            acc[1][2] = fmaf(av.y, bv.z, acc[1][2]);
            acc[1][3] = fmaf(av.y, bv.w, acc[1][3]);
            acc[2][0] = fmaf(av.z, bv.x, acc[2][0]);
            acc[2][1] = fmaf(av.z, bv.y, acc[2][1]);
            acc[2][2] = fmaf(av.z, bv.z, acc[2][2]);
            acc[2][3] = fmaf(av.z, bv.w, acc[2][3]);
            acc[3][0] = fmaf(av.w, bv.x, acc[3][0]);
            acc[3][1] = fmaf(av.w, bv.y, acc[3][1]);
            acc[3][2] = fmaf(av.w, bv.z, acc[3][2]);
            acc[3][3] = fmaf(av.w, bv.w, acc[3][3]);
        }
        __syncthreads();
    }
    float4 bia = *(const float4*)(bias + bn + tn);
#pragma unroll
    for (int r = 0; r < 4; ++r) {
        float4 o;
        o.x = acc[r][0] + bia.x; o.y = acc[r][1] + bia.y;
        o.z = acc[r][2] + bia.z; o.w = acc[r][3] + bia.w;
        *(float4*)(C + (size_t)(bm + tm + r) * 256 + bn + tn) = o;
    }
}

// ---------------------------------------------------------------------------
// transpose_k: Kw [B*L, 256] -> Kt [B, H, HD, L]
// ---------------------------------------------------------------------------
__global__ __launch_bounds__(256) void transpose_k(
    const float* __restrict__ Kw, float* __restrict__ Kt)
{
    __shared__ float tile[128][33];
    int bh = blockIdx.x;
    int b = bh >> 3, h = bh & 7;
    int l0 = blockIdx.y * 128;
    int tid = threadIdx.x;

    int tr = tid >> 3;
    int tc = (tid & 7) * 4;
#pragma unroll
    for (int p = 0; p < 4; ++p) {
        int ll = p * 32 + tr;
        float4 v = *(const float4*)(Kw + ((size_t)(b * L_SEQ + l0 + ll)) * 256 + h * HD + tc);
        tile[ll][tc + 0] = v.x; tile[ll][tc + 1] = v.y;
        tile[ll][tc + 2] = v.z; tile[ll][tc + 3] = v.w;
    }
    __syncthreads();

    float* out = Kt + (size_t)bh * (HD * L_SEQ);
#pragma unroll
    for (int it = 0; it < 16; ++it) {
        int flat = it * 256 + tid;
        int d = flat >> 7;
        int l = flat & 127;
        out[(size_t)d * L_SEQ + l0 + l] = tile[l][d];
    }
}

// ---------------------------------------------------------------------------
// edge_bias_mfma v2: VALU-lean.
//  Stage A: 16x MFMA -> X = relu(EFaug @ W1aug); pack to bf16 via +0x8000
//           round + v_perm (3 VALU per 2 elems); NO per-element stats.
//  Stage B: per kc: ds_read_b128 X-frag; MFMA #1: X @ [w2g | 1 | 0] -> dots
//           (cols 0-7) and sum(x) (col 8); MFMA #2: X @ X^T -> diag = sum(x^2).
//  Epilogue: per row r: sm from col-8 lane, sq from X-X^T diag lane (static
//           lane shuffles), LN fold, pack, store.
// ---------------------------------------------------------------------------
__global__ __launch_bounds__(256) void edge_bias_mfma(
    const float* __restrict__ EF, const ushort* __restrict__ W1G,
    const ushort* __restrict__ B2G, const float* __restrict__ tail,
    ushort* __restrict__ E2)
{
    __shared__ __align__(16) char xt[4 * 16 * 528];  // 33792 B, per-wave tiles
    int tid = threadIdx.x;
    int wv = tid >> 6, lane = tid & 63;
    int q = lane >> 4, n = lane & 15;
    char* myx = xt + wv * (16 * 528);

    int bi = blockIdx.x;            // b*512 + i
    int b = bi >> 9, i = bi & 511;
    size_t rowbase = (size_t)bi * 512;

    short8 w1f[16];
#pragma unroll
    for (int t = 0; t < 16; ++t)
        w1f[t] = *(const short8*)(W1G + (t * 64 + lane) * 8);
    short8 b2f[8];
#pragma unroll
    for (int kc = 0; kc < 8; ++kc)
        b2f[kc] = *(const short8*)(B2G + (kc * 64 + lane) * 8);

    float shv = tail[n];
    float bbv = tail[8 + n];
    const ushort ONE = 0x3F80;
    const float inv256 = 1.0f / 256.0f;

    for (int iter = 0; iter < 8; ++iter) {
        int jb = iter * 64 + wv * 16;
        const float* efp = EF + (rowbase + jb + n) * 5;
        float ev[5];
#pragma unroll
        for (int e = 0; e < 5; ++e) ev[e] = efp[e];

        // cheap hi/lo split: hi = truncate, lo = round(x - hi)
        ushort hh[5], llo[5];
#pragma unroll
        for (int e = 0; e < 5; ++e) {
            ushort hi = (ushort)(fbits(ev[e]) >> 16);
            hh[e] = hi;
            llo[e] = (ushort)((fbits(ev[e] - bf2f(hi)) + 0x8000u) >> 16);
        }
        short8 ef8;
        ef8[0] = (short)(q == 0 ? hh[0] : q == 1 ? hh[3] : q == 2 ? ONE : 0);
        ef8[1] = (short)(q == 0 ? hh[1] : q == 1 ? hh[4] : 0);
        ef8[2] = (short)(q == 0 ? hh[2] : q == 1 ? llo[0] : 0);
        ef8[3] = (short)(q == 0 ? hh[3] : q == 1 ? llo[1] : 0);
        ef8[4] = (short)(q == 0 ? hh[4] : q == 1 ? llo[2] : 0);
        ef8[5] = (short)(q == 0 ? hh[0] : q == 1 ? llo[3] : 0);
        ef8[6] = (short)(q == 0 ? hh[1] : q == 1 ? llo[4] : 0);
        ef8[7] = (short)(q == 0 ? hh[2] : q == 1 ? ONE : 0);

        // ---- Stage A: X tiles -> LDS (bf16), no VALU stats
#pragma unroll
        for (int t = 0; t < 16; ++t) {
            f32x4 z = {0.f, 0.f, 0.f, 0.f};
            f32x4 d1 = __builtin_amdgcn_mfma_f32_16x16x32_bf16(w1f[t], ef8, z, 0, 0, 0);
            float x0 = fmaxf(d1[0], 0.f);
            float x1 = fmaxf(d1[1], 0.f);
            float x2 = fmaxf(d1[2], 0.f);
            float x3 = fmaxf(d1[3], 0.f);
            uint2 pk;
            pk.x = pack_bf16rnd(x0, x1);
            pk.y = pack_bf16rnd(x2, x3);
            *(uint2*)(myx + n * 528 + t * 32 + q * 8) = pk;
        }

        // ---- Stage B: dots+sum via B2, sumsq via X X^T
        f32x4 acc  = {0.f, 0.f, 0.f, 0.f};
        f32x4 acc2 = {0.f, 0.f, 0.f, 0.f};
#pragma unroll
        for (int kc = 0; kc < 8; ++kc) {
            short8 a = *(const short8*)(myx + n * 528 + kc * 64 + q * 16);
            acc  = __builtin_amdgcn_mfma_f32_16x16x32_bf16(a, b2f[kc], acc, 0, 0, 0);
            acc2 = __builtin_amdgcn_mfma_f32_16x16x32_bf16(a, a, acc2, 0, 0, 0);
        }

        // ---- Epilogue: LN fold. row p = q*4+r; sm at lane (base+8) same reg;
        //      sq (diag of X X^T) at lane base+(base>>2)+r, reg r.
        int base = lane & 48;
        float er[4];
#pragma unroll
        for (int r = 0; r < 4; ++r) {
            float sm = __shfl(acc[r], base + 8);
            float sq = __shfl(acc2[r], base + (base >> 2) + r);
            float dot = acc[r];
            float mu = sm * inv256;
            float var = fmaf(-mu, mu, sq * inv256);
            float rs = rsqrtf(var + 1e-5f);
            er[r] = fmaf(dot - mu * shv, rs, bbv);
        }
        if (n < 8) {
            uint2 outv;
            outv.x = pack_bf16rnd(er[0], er[1]);
            outv.y = pack_bf16rnd(er[2], er[3]);
            size_t basep = (((size_t)(b * NH + n) * L_SEQ + i) * L_SEQ) + jb + q * 4;
            *(uint2*)(E2 + basep) = outv;
        }
    }
}

// ---------------------------------------------------------------------------
// attn: unchanged from round 4 (out of top-5).
// ---------------------------------------------------------------------------
__global__ __launch_bounds__(256, 3) void attn_kernel(
    const float* __restrict__ Q, const float* __restrict__ Kt,
    const float* __restrict__ V, const ushort* __restrict__ E2,
    const int* __restrict__ MSK, float* __restrict__ Y)
{
    __shared__ float stage[4096];       // 16 KB: K chunk [32][128] / V chunk [128][32]
    __shared__ float pbuf[4][4][520];   // per-wave p rows (fp32)
    __shared__ float qs_t[32][16];      // q transposed: [d][row]

    int bh = blockIdx.x;
    int b = bh >> 3, h = bh & 7;
    int tid = threadIdx.x;
    int wv = tid >> 6, lane = tid & 63;
    int i0 = blockIdx.y * 16;
    int i = i0 + wv * 4;

    const float* Ktb = Kt + (size_t)bh * (HD * L_SEQ);
    const float* Vb  = V + (size_t)b * L_SEQ * D_EMB + h * HD;

    size_t erow = ((size_t)bh * L_SEQ + i) * L_SEQ;
    size_t mrow = ((size_t)b * L_SEQ + i) * L_SEQ;

    unsigned int e2p[4][4];
    int2 mkp[4][4];
#pragma unroll
    for (int r = 0; r < 4; ++r)
#pragma unroll
        for (int c = 0; c < 4; ++c) {
            int j = c * 128 + 2 * lane;
            e2p[r][c] = *(const unsigned int*)(E2 + erow + (size_t)r * L_SEQ + j);
            mkp[r][c] = *(const int2*)(MSK + mrow + (size_t)r * L_SEQ + j);
        }

    if (tid < 128) {
        int r = tid >> 3, c4 = (tid & 7) * 4;
        float4 qv = *(const float4*)(Q + ((size_t)(b * L_SEQ + i0 + r)) * 256 + h * HD + c4);
        qs_t[c4 + 0][r] = qv.x; qs_t[c4 + 1][r] = qv.y;
        qs_t[c4 + 2][r] = qv.z; qs_t[c4 + 3][r] = qv.w;
    }

    float s[4][8];
#pragma unroll
    for (int r = 0; r < 4; ++r)
#pragma unroll
        for (int t = 0; t < 8; ++t) s[r][t] = 0.f;

    for (int c = 0; c < 4; ++c) {
        if (c) __syncthreads();
        {
            int d0 = tid >> 5, jj = (tid & 31) * 4;
#pragma unroll
            for (int p = 0; p < 4; ++p) {
                int d = p * 8 + d0;
                float4 kv = *(const float4*)(Ktb + (size_t)d * L_SEQ + c * 128 + jj);
                *(float4*)&stage[d * 128 + jj] = kv;
            }
        }
        __syncthreads();
        int c2 = c * 2;
#pragma unroll 8
        for (int d = 0; d < HD; ++d) {
            float4 q4 = *(const float4*)&qs_t[d][wv * 4];
            float2 kv = *(const float2*)&stage[d * 128 + 2 * lane];
            s[0][c2]     = fmaf(q4.x, kv.x, s[0][c2]);
            s[0][c2 + 1] = fmaf(q4.x, kv.y, s[0][c2 + 1]);
            s[1][c2]     = fmaf(q4.y, kv.x, s[1][c2]);
            s[1][c2 + 1] = fmaf(q4.y, kv.y, s[1][c2 + 1]);
            s[2][c2]     = fmaf(q4.z, kv.x, s[2][c2]);
            s[2][c2 + 1] = fmaf(q4.z, kv.y, s[2][c2 + 1]);
            s[3][c2]     = fmaf(q4.w, kv.x, s[3][c2]);
            s[3][c2 + 1] = fmaf(q4.w, kv.y, s[3][c2 + 1]);
        }
    }

    const float scl = 0.17677669529663687f;  // 1/sqrt(32)
#pragma unroll
    for (int r = 0; r < 4; ++r) {
        float sv[8];
        float m = -3.0e38f;
#pragma unroll
        for (int idx = 0; idx < 8; ++idx) {
            int c = idx >> 1, u = idx & 1;
            unsigned int pk = e2p[r][c];
            float e = bf2f((ushort)(u ? (pk >> 16) : (pk & 0xffff)));
            int mk = u ? mkp[r][c].y : mkp[r][c].x;
            float v = (mk != 0) ? fmaf(s[r][idx], scl, e) : -1e30f;
            sv[idx] = v;
            m = fmaxf(m, v);
        }
#pragma unroll
        for (int o = 32; o > 0; o >>= 1) m = fmaxf(m, __shfl_xor(m, o));
        float ssum = 0.f;
#pragma unroll
        for (int idx = 0; idx < 8; ++idx) {
            float p = __expf(sv[idx] - m);
            sv[idx] = p;
            ssum += p;
        }
#pragma unroll
        for (int o = 32; o > 0; o >>= 1) ssum += __shfl_xor(ssum, o);
        float inv = 1.0f / ssum;
#pragma unroll
        for (int c = 0; c < 4; ++c) {
            float2 w;
            w.x = sv[c * 2] * inv;
            w.y = sv[c * 2 + 1] * inv;
            *(float2*)&pbuf[wv][r][c * 128 + 2 * lane] = w;
        }
    }

    int dg = lane >> 3, js = lane & 7;
    float4 acc[4];
#pragma unroll
    for (int r = 0; r < 4; ++r) { acc[r].x = 0.f; acc[r].y = 0.f; acc[r].z = 0.f; acc[r].w = 0.f; }

    for (int c = 0; c < 4; ++c) {
        __syncthreads();
        {
            int j0 = tid >> 3, dd = (tid & 7) * 4;
#pragma unroll
            for (int p = 0; p < 4; ++p) {
                int j = p * 32 + j0;
                float4 vv = *(const float4*)(Vb + (size_t)(c * 128 + j) * D_EMB + dd);
                *(float4*)&stage[j * 32 + dd] = vv;
            }
        }
        __syncthreads();
#pragma unroll
        for (int jb = 0; jb < 16; ++jb) {
            int jj = jb * 8 + js;
            float4 v4 = *(const float4*)&stage[jj * 32 + dg * 4];
#pragma unroll
            for (int r = 0; r < 4; ++r) {
                float p = pbuf[wv][r][c * 128 + jj];
                acc[r].x = fmaf(p, v4.x, acc[r].x);
                acc[r].y = fmaf(p, v4.y, acc[r].y);
                acc[r].z = fmaf(p, v4.z, acc[r].z);
                acc[r].w = fmaf(p, v4.w, acc[r].w);
            }
        }
    }

#pragma unroll
    for (int off = 1; off < 8; off <<= 1) {
#pragma unroll
        for (int r = 0; r < 4; ++r) {
            acc[r].x += __shfl_xor(acc[r].x, off);
            acc[r].y += __shfl_xor(acc[r].y, off);
            acc[r].z += __shfl_xor(acc[r].z, off);
            acc[r].w += __shfl_xor(acc[r].w, off);
        }
    }
    if (js == 0) {
#pragma unroll
        for (int r = 0; r < 4; ++r)
            *(float4*)(Y + ((size_t)(b * L_SEQ + i + r)) * 256 + h * HD + dg * 4) = acc[r];
    }
}

// ---------------------------------------------------------------------------
extern "C" void kernel_launch(void* const* d_in, const int* in_sizes, int n_in,
                              void* d_out, int out_size, void* d_ws, size_t ws_size,
                              hipStream_t stream)
{
    const float* key   = (const float*)d_in[0];
    const float* value = (const float*)d_in[1];
    const float* query = (const float*)d_in[2];
    const int*   msk   = (const int*)d_in[3];
    const float* ef    = (const float*)d_in[4];
    const float* Wk  = (const float*)d_in[5];  const float* bk  = (const float*)d_in[6];
    const float* Wq  = (const float*)d_in[7];  const float* bq  = (const float*)d_in[8];
    const float* Wv  = (const float*)d_in[9];  const float* bv  = (const float*)d_in[10];
    const float* Wp  = (const float*)d_in[11]; const float* bp  = (const float*)d_in[12];
    const float* We1 = (const float*)d_in[13]; const float* be1 = (const float*)d_in[14];
    const float* lng = (const float*)d_in[15]; const float* lnb = (const float*)d_in[16];
    const float* We2 = (const float*)d_in[17]; const float* be2 = (const float*)d_in[18];

    const int MTOK = 4 * L_SEQ;          // 2048 rows
    const int NELT = MTOK * D_EMB;       // 524288

    float* ws    = (float*)d_ws;
    float* Qw    = ws;
    float* Kw    = Qw + NELT;
    float* Vw    = Kw + NELT;
    float* Yw    = Vw + NELT;
    float* Ktw   = Yw + NELT;
    ushort* W1G  = (ushort*)(Ktw + NELT);   // 8192 bf16
    ushort* B2G  = W1G + 8192;              // 4096 bf16
    float* tail  = (float*)(B2G + 4096);    // 32 floats
    ushort* E2   = (ushort*)(tail + 32);    // 8388608 bf16 (~16.8 MB)

    hipLaunchKernelGGL(prep_kernel, dim3(1), dim3(256), 0, stream,
                       We1, be1, lng, lnb, We2, be2, W1G, B2G, tail);
    hipLaunchKernelGGL(gemm256, dim3(32, 4, 3), dim3(256), 0, stream,
                       query, Wq, bq, Qw,
                       key,   Wk, bk, Kw,
                       value, Wv, bv, Vw);
    hipLaunchKernelGGL(transpose_k, dim3(32, 4), dim3(256), 0, stream,
                       Kw, Ktw);
    hipLaunchKernelGGL(edge_bias_mfma, dim3(2048), dim3(256), 0, stream,
                       ef, W1G, B2G, tail, E2);
    hipLaunchKernelGGL(attn_kernel, dim3(32, 32), dim3(256), 0, stream,
                       Qw, Ktw, Vw, E2, msk, Yw);
    hipLaunchKernelGGL(gemm256, dim3(32, 4, 1), dim3(256), 0, stream,
                       Yw, Wp, bp, (float*)d_out,
                       Yw, Wp, bp, (float*)d_out,
                       Yw, Wp, bp, (float*)d_out);
}

// Round 6
// 237.584 us; speedup vs baseline: 1.4608x; 1.0772x over previous
//
#include <hip/hip_runtime.h>
#include <hip/hip_bf16.h>

#define L_SEQ 512
#define D_EMB 256
#define NH 8
#define HD 32
#define LL (L_SEQ * L_SEQ)   // 262144

typedef __attribute__((ext_vector_type(8))) short short8;
typedef __attribute__((ext_vector_type(4))) float f32x4;
typedef unsigned short ushort;

__device__ __forceinline__ float bf2f(ushort u) {
    unsigned int x = ((unsigned int)u) << 16;
    float f;
    __builtin_memcpy(&f, &x, 4);
    return f;
}
__device__ __forceinline__ ushort f2bf(float x) {   // RNE (host-quality), prep only
    __hip_bfloat16 h = __float2bfloat16(x);
    ushort u;
    __builtin_memcpy(&u, &h, 2);
    return u;
}
__device__ __forceinline__ unsigned int fbits(float x) {
    unsigned int u;
    __builtin_memcpy(&u, &x, 4);
    return u;
}
__device__ __forceinline__ float asf(unsigned int u) {
    float f;
    __builtin_memcpy(&f, &u, 4);
    return f;
}
// pack bf16(a) | bf16(b)<<16, nearest-ties-away rounding, 3 VALU ops
__device__ __forceinline__ unsigned int pack_bf16rnd(float a, float b) {
    return __builtin_amdgcn_perm(fbits(b) + 0x8000u, fbits(a) + 0x8000u, 0x07060302u);
}
// hi/lo split of two floats: .x = packed hi pair, .y = packed lo pair
__device__ __forceinline__ uint2 cvt_hilo2(float v0, float v1) {
    unsigned int hi = pack_bf16rnd(v0, v1);
    float h0 = asf(hi << 16);
    float h1 = asf(hi & 0xffff0000u);
    unsigned int lo = pack_bf16rnd(v0 - h0, v1 - h1);
    uint2 r; r.x = hi; r.y = lo;
    return r;
}

// ---------------------------------------------------------------------------
// prep: build MFMA fragment tables for the edge kernel + LN-fold tails.
// (unchanged from round 5)
// ---------------------------------------------------------------------------
__global__ __launch_bounds__(256) void prep_kernel(
    const float* __restrict__ We1, const float* __restrict__ be1,
    const float* __restrict__ g,   const float* __restrict__ bta,
    const float* __restrict__ We2, const float* __restrict__ be2,
    ushort* __restrict__ W1G, ushort* __restrict__ B2G, float* __restrict__ tail)
{
    int t = threadIdx.x;  // 0..255
    __shared__ float red[16][256];
    float gd = g[t], bd = bta[t];
#pragma unroll
    for (int h = 0; h < 8; ++h) {
        float w2 = We2[t * 8 + h];
        red[h][t] = gd * w2;
        red[8 + h][t] = bd * w2;
    }
    __syncthreads();
    for (int off = 128; off > 0; off >>= 1) {
        if (t < off) {
#pragma unroll
            for (int row = 0; row < 16; ++row) red[row][t] += red[row][t + off];
        }
        __syncthreads();
    }
    if (t < 8) {
        tail[t] = red[t][0];
        tail[8 + t] = red[8 + t][0] + be2[t];
    }
    if (t >= 16 && t < 32) tail[t] = 0.f;

    for (int idx = t; idx < 8192; idx += 256) {
        int j = idx & 7, lane = (idx >> 3) & 63, tile = idx >> 9;
        int m = lane & 15, q = lane >> 4;
        int k = q * 8 + j;
        int d = tile * 16 + m;
        float v = 0.f;
        bool lo = false;
        if (k < 5)        v = We1[k * 256 + d];
        else if (k < 10)  { v = We1[(k - 5) * 256 + d]; lo = true; }
        else if (k < 15)  v = We1[(k - 10) * 256 + d];
        else if (k == 15) v = be1[d];
        else if (k == 16) { v = be1[d]; lo = true; }
        ushort hi = f2bf(v);
        W1G[idx] = lo ? f2bf(v - bf2f(hi)) : hi;
    }
    for (int idx = t; idx < 4096; idx += 256) {
        int j = idx & 7, lane = (idx >> 3) & 63, kc = idx >> 9;
        int n = lane & 15, q = lane >> 4;
        int d = kc * 32 + q * 8 + j;
        ushort out;
        if (n < 8)       out = f2bf(g[d] * We2[d * 8 + n]);
        else if (n == 8) out = 0x3F80;   // 1.0 bf16
        else             out = 0;
        B2G[idx] = out;
    }
}

// ---------------------------------------------------------------------------
// prep_w: transpose + hi/lo-split the 4 projection weights.
// Wt_hi/Wt_lo layout: [matrix][n][k] (n-major, 256 k per row).
// ---------------------------------------------------------------------------
__global__ __launch_bounds__(256) void prep_w(
    const float* __restrict__ Wq, const float* __restrict__ Wk,
    const float* __restrict__ Wv, const float* __restrict__ Wp,
    ushort* __restrict__ WThi, ushort* __restrict__ WTlo)
{
    int w = blockIdx.x;           // 0..3
    const float* W = (w == 0) ? Wq : (w == 1) ? Wk : (w == 2) ? Wv : Wp;
    ushort* dh = WThi + (size_t)w * 65536;
    ushort* dl = WTlo + (size_t)w * 65536;

    int tid = threadIdx.x;
    int n = blockIdx.y * 16 + (tid >> 4);
    int k0 = (tid & 15) * 16;

    ushort hbuf[16], lbuf[16];
#pragma unroll
    for (int kk = 0; kk < 16; ++kk) {
        float v = W[(size_t)(k0 + kk) * 256 + n];
        unsigned int hb = fbits(v) + 0x8000u;
        ushort hi = (ushort)(hb >> 16);
        float res = v - bf2f(hi);
        hbuf[kk] = hi;
        lbuf[kk] = (ushort)((fbits(res) + 0x8000u) >> 16);
    }
    *(short8*)(dh + (size_t)n * 256 + k0)     = *(short8*)&hbuf[0];
    *(short8*)(dh + (size_t)n * 256 + k0 + 8) = *(short8*)&hbuf[8];
    *(short8*)(dl + (size_t)n * 256 + k0)     = *(short8*)&lbuf[0];
    *(short8*)(dl + (size_t)n * 256 + k0 + 8) = *(short8*)&lbuf[8];
}

// ---------------------------------------------------------------------------
// gemm_mfma: C[2048,256] = A[2048,256] @ W[256,256] + bias, fp32-accurate via
// bf16 hi/lo split (3-term MFMA: Ahi*Blo + Alo*Bhi + Ahi*Bhi).
// Block 64x64, 4 waves; wave = 64(M) x 16(N). A staged fp32->hi/lo bf16 via
// LDS per 32-k chunk; B-frags straight from the prep_w [n][k] tables (L2).
// blockIdx.z selects one of up to 3 problems.
// ---------------------------------------------------------------------------
__global__ __launch_bounds__(256) void gemm_mfma(
    const float* __restrict__ A0, const ushort* __restrict__ H0,
    const ushort* __restrict__ L0, const float* __restrict__ b0,
    float* __restrict__ C0,
    const float* __restrict__ A1, const ushort* __restrict__ H1,
    const ushort* __restrict__ L1, const float* __restrict__ b1,
    float* __restrict__ C1,
    const float* __restrict__ A2, const ushort* __restrict__ H2,
    const ushort* __restrict__ L2, const float* __restrict__ b2,
    float* __restrict__ C2)
{
    const float* A; const ushort* BH; const ushort* BL;
    const float* bias; float* C;
    if (blockIdx.z == 0)      { A = A0; BH = H0; BL = L0; bias = b0; C = C0; }
    else if (blockIdx.z == 1) { A = A1; BH = H1; BL = L1; bias = b1; C = C1; }
    else                      { A = A2; BH = H2; BL = L2; bias = b2; C = C2; }

    __shared__ ushort Ahi[64][40];   // 40-short pitch (80 B) -> spread banks
    __shared__ ushort Alo[64][40];

    int tid = threadIdx.x;
    int wv = tid >> 6, lane = tid & 63;
    int m = lane & 15, quad = lane >> 4;
    int bm = blockIdx.x * 64, bn = blockIdx.y * 64;

    int sm = tid >> 2, sg = (tid & 3) * 8;        // staging coords
    const float* Arow = A + (size_t)(bm + sm) * 256 + sg;

    int nrow = bn + wv * 16 + m;
    const ushort* bhp = BH + (size_t)nrow * 256 + quad * 8;
    const ushort* blp = BL + (size_t)nrow * 256 + quad * 8;

    f32x4 acc[4];
#pragma unroll
    for (int mt = 0; mt < 4; ++mt) acc[mt] = (f32x4){0.f, 0.f, 0.f, 0.f};

    for (int k0 = 0; k0 < 256; k0 += 32) {
        // stage A chunk: 8 fp32 -> hi/lo bf16
        float4 a0 = *(const float4*)(Arow + k0);
        float4 a1 = *(const float4*)(Arow + k0 + 4);
        uint2 c0 = cvt_hilo2(a0.x, a0.y);
        uint2 c1 = cvt_hilo2(a0.z, a0.w);
        uint2 c2 = cvt_hilo2(a1.x, a1.y);
        uint2 c3 = cvt_hilo2(a1.z, a1.w);
        if (k0) __syncthreads();
        uint4 hq; hq.x = c0.x; hq.y = c1.x; hq.z = c2.x; hq.w = c3.x;
        uint4 lq; lq.x = c0.y; lq.y = c1.y; lq.z = c2.y; lq.w = c3.y;
        *(uint4*)&Ahi[sm][sg] = hq;
        *(uint4*)&Alo[sm][sg] = lq;
        __syncthreads();

        short8 bhi = *(const short8*)(bhp + k0);
        short8 blo = *(const short8*)(blp + k0);
#pragma unroll
        for (int mt = 0; mt < 4; ++mt) {
            short8 ahi = *(const short8*)&Ahi[mt * 16 + m][quad * 8];
            short8 alo = *(const short8*)&Alo[mt * 16 + m][quad * 8];
            acc[mt] = __builtin_amdgcn_mfma_f32_16x16x32_bf16(ahi, blo, acc[mt], 0, 0, 0);
            acc[mt] = __builtin_amdgcn_mfma_f32_16x16x32_bf16(alo, bhi, acc[mt], 0, 0, 0);
            acc[mt] = __builtin_amdgcn_mfma_f32_16x16x32_bf16(ahi, bhi, acc[mt], 0, 0, 0);
        }
    }

    float bn_bias = bias[nrow];
#pragma unroll
    for (int mt = 0; mt < 4; ++mt) {
#pragma unroll
        for (int r = 0; r < 4; ++r) {
            C[(size_t)(bm + mt * 16 + quad * 4 + r) * 256 + nrow] = acc[mt][r] + bn_bias;
        }
    }
}

// ---------------------------------------------------------------------------
// transpose_k: Kw [B*L, 256] -> Kt [B, H, HD, L]  (unchanged)
// ---------------------------------------------------------------------------
__global__ __launch_bounds__(256) void transpose_k(
    const float* __restrict__ Kw, float* __restrict__ Kt)
{
    __shared__ float tile[128][33];
    int bh = blockIdx.x;
    int b = bh >> 3, h = bh & 7;
    int l0 = blockIdx.y * 128;
    int tid = threadIdx.x;

    int tr = tid >> 3;
    int tc = (tid & 7) * 4;
#pragma unroll
    for (int p = 0; p < 4; ++p) {
        int ll = p * 32 + tr;
        float4 v = *(const float4*)(Kw + ((size_t)(b * L_SEQ + l0 + ll)) * 256 + h * HD + tc);
        tile[ll][tc + 0] = v.x; tile[ll][tc + 1] = v.y;
        tile[ll][tc + 2] = v.z; tile[ll][tc + 3] = v.w;
    }
    __syncthreads();

    float* out = Kt + (size_t)bh * (HD * L_SEQ);
#pragma unroll
    for (int it = 0; it < 16; ++it) {
        int flat = it * 256 + tid;
        int d = flat >> 7;
        int l = flat & 127;
        out[(size_t)d * L_SEQ + l0 + l] = tile[l][d];
    }
}

// ---------------------------------------------------------------------------
// edge_bias_mfma v2 (unchanged from round 5)
// ---------------------------------------------------------------------------
__global__ __launch_bounds__(256) void edge_bias_mfma(
    const float* __restrict__ EF, const ushort* __restrict__ W1G,
    const ushort* __restrict__ B2G, const float* __restrict__ tail,
    ushort* __restrict__ E2)
{
    __shared__ __align__(16) char xt[4 * 16 * 528];  // 33792 B, per-wave tiles
    int tid = threadIdx.x;
    int wv = tid >> 6, lane = tid & 63;
    int q = lane >> 4, n = lane & 15;
    char* myx = xt + wv * (16 * 528);

    int bi = blockIdx.x;            // b*512 + i
    int b = bi >> 9, i = bi & 511;
    size_t rowbase = (size_t)bi * 512;

    short8 w1f[16];
#pragma unroll
    for (int t = 0; t < 16; ++t)
        w1f[t] = *(const short8*)(W1G + (t * 64 + lane) * 8);
    short8 b2f[8];
#pragma unroll
    for (int kc = 0; kc < 8; ++kc)
        b2f[kc] = *(const short8*)(B2G + (kc * 64 + lane) * 8);

    float shv = tail[n];
    float bbv = tail[8 + n];
    const ushort ONE = 0x3F80;
    const float inv256 = 1.0f / 256.0f;

    for (int iter = 0; iter < 8; ++iter) {
        int jb = iter * 64 + wv * 16;
        const float* efp = EF + (rowbase + jb + n) * 5;
        float ev[5];
#pragma unroll
        for (int e = 0; e < 5; ++e) ev[e] = efp[e];

        ushort hh[5], llo[5];
#pragma unroll
        for (int e = 0; e < 5; ++e) {
            ushort hi = (ushort)(fbits(ev[e]) >> 16);
            hh[e] = hi;
            llo[e] = (ushort)((fbits(ev[e] - bf2f(hi)) + 0x8000u) >> 16);
        }
        short8 ef8;
        ef8[0] = (short)(q == 0 ? hh[0] : q == 1 ? hh[3] : q == 2 ? ONE : 0);
        ef8[1] = (short)(q == 0 ? hh[1] : q == 1 ? hh[4] : 0);
        ef8[2] = (short)(q == 0 ? hh[2] : q == 1 ? llo[0] : 0);
        ef8[3] = (short)(q == 0 ? hh[3] : q == 1 ? llo[1] : 0);
        ef8[4] = (short)(q == 0 ? hh[4] : q == 1 ? llo[2] : 0);
        ef8[5] = (short)(q == 0 ? hh[0] : q == 1 ? llo[3] : 0);
        ef8[6] = (short)(q == 0 ? hh[1] : q == 1 ? llo[4] : 0);
        ef8[7] = (short)(q == 0 ? hh[2] : q == 1 ? ONE : 0);

#pragma unroll
        for (int t = 0; t < 16; ++t) {
            f32x4 z = {0.f, 0.f, 0.f, 0.f};
            f32x4 d1 = __builtin_amdgcn_mfma_f32_16x16x32_bf16(w1f[t], ef8, z, 0, 0, 0);
            float x0 = fmaxf(d1[0], 0.f);
            float x1 = fmaxf(d1[1], 0.f);
            float x2 = fmaxf(d1[2], 0.f);
            float x3 = fmaxf(d1[3], 0.f);
            uint2 pk;
            pk.x = pack_bf16rnd(x0, x1);
            pk.y = pack_bf16rnd(x2, x3);
            *(uint2*)(myx + n * 528 + t * 32 + q * 8) = pk;
        }

        f32x4 acc  = {0.f, 0.f, 0.f, 0.f};
        f32x4 acc2 = {0.f, 0.f, 0.f, 0.f};
#pragma unroll
        for (int kc = 0; kc < 8; ++kc) {
            short8 a = *(const short8*)(myx + n * 528 + kc * 64 + q * 16);
            acc  = __builtin_amdgcn_mfma_f32_16x16x32_bf16(a, b2f[kc], acc, 0, 0, 0);
            acc2 = __builtin_amdgcn_mfma_f32_16x16x32_bf16(a, a, acc2, 0, 0, 0);
        }

        int base = lane & 48;
        float er[4];
#pragma unroll
        for (int r = 0; r < 4; ++r) {
            float sm = __shfl(acc[r], base + 8);
            float sq = __shfl(acc2[r], base + (base >> 2) + r);
            float dot = acc[r];
            float mu = sm * inv256;
            float var = fmaf(-mu, mu, sq * inv256);
            float rs = rsqrtf(var + 1e-5f);
            er[r] = fmaf(dot - mu * shv, rs, bbv);
        }
        if (n < 8) {
            uint2 outv;
            outv.x = pack_bf16rnd(er[0], er[1]);
            outv.y = pack_bf16rnd(er[2], er[3]);
            size_t basep = (((size_t)(b * NH + n) * L_SEQ + i) * L_SEQ) + jb + q * 4;
            *(uint2*)(E2 + basep) = outv;
        }
    }
}

// ---------------------------------------------------------------------------
// attn: unchanged from round 4/5.
// ---------------------------------------------------------------------------
__global__ __launch_bounds__(256, 3) void attn_kernel(
    const float* __restrict__ Q, const float* __restrict__ Kt,
    const float* __restrict__ V, const ushort* __restrict__ E2,
    const int* __restrict__ MSK, float* __restrict__ Y)
{
    __shared__ float stage[4096];       // 16 KB: K chunk [32][128] / V chunk [128][32]
    __shared__ float pbuf[4][4][520];   // per-wave p rows (fp32)
    __shared__ float qs_t[32][16];      // q transposed: [d][row]

    int bh = blockIdx.x;
    int b = bh >> 3, h = bh & 7;
    int tid = threadIdx.x;
    int wv = tid >> 6, lane = tid & 63;
    int i0 = blockIdx.y * 16;
    int i = i0 + wv * 4;

    const float* Ktb = Kt + (size_t)bh * (HD * L_SEQ);
    const float* Vb  = V + (size_t)b * L_SEQ * D_EMB + h * HD;

    size_t erow = ((size_t)bh * L_SEQ + i) * L_SEQ;
    size_t mrow = ((size_t)b * L_SEQ + i) * L_SEQ;

    unsigned int e2p[4][4];
    int2 mkp[4][4];
#pragma unroll
    for (int r = 0; r < 4; ++r)
#pragma unroll
        for (int c = 0; c < 4; ++c) {
            int j = c * 128 + 2 * lane;
            e2p[r][c] = *(const unsigned int*)(E2 + erow + (size_t)r * L_SEQ + j);
            mkp[r][c] = *(const int2*)(MSK + mrow + (size_t)r * L_SEQ + j);
        }

    if (tid < 128) {
        int r = tid >> 3, c4 = (tid & 7) * 4;
        float4 qv = *(const float4*)(Q + ((size_t)(b * L_SEQ + i0 + r)) * 256 + h * HD + c4);
        qs_t[c4 + 0][r] = qv.x; qs_t[c4 + 1][r] = qv.y;
        qs_t[c4 + 2][r] = qv.z; qs_t[c4 + 3][r] = qv.w;
    }

    float s[4][8];
#pragma unroll
    for (int r = 0; r < 4; ++r)
#pragma unroll
        for (int t = 0; t < 8; ++t) s[r][t] = 0.f;

    for (int c = 0; c < 4; ++c) {
        if (c) __syncthreads();
        {
            int d0 = tid >> 5, jj = (tid & 31) * 4;
#pragma unroll
            for (int p = 0; p < 4; ++p) {
                int d = p * 8 + d0;
                float4 kv = *(const float4*)(Ktb + (size_t)d * L_SEQ + c * 128 + jj);
                *(float4*)&stage[d * 128 + jj] = kv;
            }
        }
        __syncthreads();
        int c2 = c * 2;
#pragma unroll 8
        for (int d = 0; d < HD; ++d) {
            float4 q4 = *(const float4*)&qs_t[d][wv * 4];
            float2 kv = *(const float2*)&stage[d * 128 + 2 * lane];
            s[0][c2]     = fmaf(q4.x, kv.x, s[0][c2]);
            s[0][c2 + 1] = fmaf(q4.x, kv.y, s[0][c2 + 1]);
            s[1][c2]     = fmaf(q4.y, kv.x, s[1][c2]);
            s[1][c2 + 1] = fmaf(q4.y, kv.y, s[1][c2 + 1]);
            s[2][c2]     = fmaf(q4.z, kv.x, s[2][c2]);
            s[2][c2 + 1] = fmaf(q4.z, kv.y, s[2][c2 + 1]);
            s[3][c2]     = fmaf(q4.w, kv.x, s[3][c2]);
            s[3][c2 + 1] = fmaf(q4.w, kv.y, s[3][c2 + 1]);
        }
    }

    const float scl = 0.17677669529663687f;  // 1/sqrt(32)
#pragma unroll
    for (int r = 0; r < 4; ++r) {
        float sv[8];
        float m = -3.0e38f;
#pragma unroll
        for (int idx = 0; idx < 8; ++idx) {
            int c = idx >> 1, u = idx & 1;
            unsigned int pk = e2p[r][c];
            float e = bf2f((ushort)(u ? (pk >> 16) : (pk & 0xffff)));
            int mk = u ? mkp[r][c].y : mkp[r][c].x;
            float v = (mk != 0) ? fmaf(s[r][idx], scl, e) : -1e30f;
            sv[idx] = v;
            m = fmaxf(m, v);
        }
#pragma unroll
        for (int o = 32; o > 0; o >>= 1) m = fmaxf(m, __shfl_xor(m, o));
        float ssum = 0.f;
#pragma unroll
        for (int idx = 0; idx < 8; ++idx) {
            float p = __expf(sv[idx] - m);
            sv[idx] = p;
            ssum += p;
        }
#pragma unroll
        for (int o = 32; o > 0; o >>= 1) ssum += __shfl_xor(ssum, o);
        float inv = 1.0f / ssum;
#pragma unroll
        for (int c = 0; c < 4; ++c) {
            float2 w;
            w.x = sv[c * 2] * inv;
            w.y = sv[c * 2 + 1] * inv;
            *(float2*)&pbuf[wv][r][c * 128 + 2 * lane] = w;
        }
    }

    int dg = lane >> 3, js = lane & 7;
    float4 acc[4];
#pragma unroll
    for (int r = 0; r < 4; ++r) { acc[r].x = 0.f; acc[r].y = 0.f; acc[r].z = 0.f; acc[r].w = 0.f; }

    for (int c = 0; c < 4; ++c) {
        __syncthreads();
        {
            int j0 = tid >> 3, dd = (tid & 7) * 4;
#pragma unroll
            for (int p = 0; p < 4; ++p) {
                int j = p * 32 + j0;
                float4 vv = *(const float4*)(Vb + (size_t)(c * 128 + j) * D_EMB + dd);
                *(float4*)&stage[j * 32 + dd] = vv;
            }
        }
        __syncthreads();
#pragma unroll
        for (int jb = 0; jb < 16; ++jb) {
            int jj = jb * 8 + js;
            float4 v4 = *(const float4*)&stage[jj * 32 + dg * 4];
#pragma unroll
            for (int r = 0; r < 4; ++r) {
                float p = pbuf[wv][r][c * 128 + jj];
                acc[r].x = fmaf(p, v4.x, acc[r].x);
                acc[r].y = fmaf(p, v4.y, acc[r].y);
                acc[r].z = fmaf(p, v4.z, acc[r].z);
                acc[r].w = fmaf(p, v4.w, acc[r].w);
            }
        }
    }

#pragma unroll
    for (int off = 1; off < 8; off <<= 1) {
#pragma unroll
        for (int r = 0; r < 4; ++r) {
            acc[r].x += __shfl_xor(acc[r].x, off);
            acc[r].y += __shfl_xor(acc[r].y, off);
            acc[r].z += __shfl_xor(acc[r].z, off);
            acc[r].w += __shfl_xor(acc[r].w, off);
        }
    }
    if (js == 0) {
#pragma unroll
        for (int r = 0; r < 4; ++r)
            *(float4*)(Y + ((size_t)(b * L_SEQ + i + r)) * 256 + h * HD + dg * 4) = acc[r];
    }
}

// ---------------------------------------------------------------------------
extern "C" void kernel_launch(void* const* d_in, const int* in_sizes, int n_in,
                              void* d_out, int out_size, void* d_ws, size_t ws_size,
                              hipStream_t stream)
{
    const float* key   = (const float*)d_in[0];
    const float* value = (const float*)d_in[1];
    const float* query = (const float*)d_in[2];
    const int*   msk   = (const int*)d_in[3];
    const float* ef    = (const float*)d_in[4];
    const float* Wk  = (const float*)d_in[5];  const float* bk  = (const float*)d_in[6];
    const float* Wq  = (const float*)d_in[7];  const float* bq  = (const float*)d_in[8];
    const float* Wv  = (const float*)d_in[9];  const float* bv  = (const float*)d_in[10];
    const float* Wp  = (const float*)d_in[11]; const float* bp  = (const float*)d_in[12];
    const float* We1 = (const float*)d_in[13]; const float* be1 = (const float*)d_in[14];
    const float* lng = (const float*)d_in[15]; const float* lnb = (const float*)d_in[16];
    const float* We2 = (const float*)d_in[17]; const float* be2 = (const float*)d_in[18];

    const int MTOK = 4 * L_SEQ;          // 2048 rows
    const int NELT = MTOK * D_EMB;       // 524288

    float* ws    = (float*)d_ws;
    float* Qw    = ws;
    float* Kw    = Qw + NELT;
    float* Vw    = Kw + NELT;
    float* Yw    = Vw + NELT;
    float* Ktw   = Yw + NELT;
    ushort* W1G  = (ushort*)(Ktw + NELT);   // 8192 bf16
    ushort* B2G  = W1G + 8192;              // 4096 bf16
    float* tail  = (float*)(B2G + 4096);    // 32 floats
    ushort* WThi = (ushort*)(tail + 32);    // 4*65536 bf16 (512 KB)
    ushort* WTlo = WThi + 4 * 65536;        // 4*65536 bf16 (512 KB)
    ushort* E2   = WTlo + 4 * 65536;        // 8388608 bf16 (~16.8 MB)

    hipLaunchKernelGGL(prep_kernel, dim3(1), dim3(256), 0, stream,
                       We1, be1, lng, lnb, We2, be2, W1G, B2G, tail);
    hipLaunchKernelGGL(prep_w, dim3(4, 16), dim3(256), 0, stream,
                       Wq, Wk, Wv, Wp, WThi, WTlo);
    // QKV projections: q uses Wt[0], k -> Wt[1], v -> Wt[2]
    hipLaunchKernelGGL(gemm_mfma, dim3(32, 4, 3), dim3(256), 0, stream,
                       query, WThi + 0 * 65536, WTlo + 0 * 65536, bq, Qw,
                       key,   WThi + 1 * 65536, WTlo + 1 * 65536, bk, Kw,
                       value, WThi + 2 * 65536, WTlo + 2 * 65536, bv, Vw);
    hipLaunchKernelGGL(transpose_k, dim3(32, 4), dim3(256), 0, stream,
                       Kw, Ktw);
    hipLaunchKernelGGL(edge_bias_mfma, dim3(2048), dim3(256), 0, stream,
                       ef, W1G, B2G, tail, E2);
    hipLaunchKernelGGL(attn_kernel, dim3(32, 32), dim3(256), 0, stream,
                       Qw, Ktw, Vw, E2, msk, Yw);
    hipLaunchKernelGGL(gemm_mfma, dim3(32, 4, 1), dim3(256), 0, stream,
                       Yw, WThi + 3 * 65536, WTlo + 3 * 65536, bp, (float*)d_out,
                       Yw, WThi + 3 * 65536, WTlo + 3 * 65536, bp, (float*)d_out,
                       Yw, WThi + 3 * 65536, WTlo + 3 * 65536, bp, (float*)d_out);
}

// Round 7
// 228.468 us; speedup vs baseline: 1.5190x; 1.0399x over previous
//
#include <hip/hip_runtime.h>
#include <hip/hip_bf16.h>

#define L_SEQ 512
#define D_EMB 256
#define NH 8
#define HD 32
#define LL (L_SEQ * L_SEQ)   // 262144

typedef __attribute__((ext_vector_type(8))) short short8;
typedef __attribute__((ext_vector_type(4))) float f32x4;
typedef unsigned short ushort;

__device__ __forceinline__ float bf2f(ushort u) {
    unsigned int x = ((unsigned int)u) << 16;
    float f;
    __builtin_memcpy(&f, &x, 4);
    return f;
}
__device__ __forceinline__ ushort f2bf(float x) {   // RNE (host-quality), prep only
    __hip_bfloat16 h = __float2bfloat16(x);
    ushort u;
    __builtin_memcpy(&u, &h, 2);
    return u;
}
__device__ __forceinline__ unsigned int fbits(float x) {
    unsigned int u;
    __builtin_memcpy(&u, &x, 4);
    return u;
}
__device__ __forceinline__ float asf(unsigned int u) {
    float f;
    __builtin_memcpy(&f, &u, 4);
    return f;
}
// pack bf16(a) | bf16(b)<<16, nearest-ties-away rounding, 3 VALU ops
__device__ __forceinline__ unsigned int pack_bf16rnd(float a, float b) {
    return __builtin_amdgcn_perm(fbits(b) + 0x8000u, fbits(a) + 0x8000u, 0x07060302u);
}
// hi16(x) | hi16(y)<<16  (one v_perm)
__device__ __forceinline__ unsigned int packhi(unsigned int y, unsigned int x) {
    return __builtin_amdgcn_perm(y, x, 0x07060302u);
}
// hi/lo split of two floats: .x = packed hi pair, .y = packed lo pair
__device__ __forceinline__ uint2 cvt_hilo2(float v0, float v1) {
    unsigned int hi = pack_bf16rnd(v0, v1);
    float h0 = asf(hi << 16);
    float h1 = asf(hi & 0xffff0000u);
    unsigned int lo = pack_bf16rnd(v0 - h0, v1 - h1);
    uint2 r; r.x = hi; r.y = lo;
    return r;
}

// ---------------------------------------------------------------------------
// prep (merged): block 0 builds the edge-kernel tables; blocks 1..64 do the
// projection-weight transpose+hi/lo-split (old prep_w).
//
// W1G row permutation (NEW): tile t, A-row m -> physical d = (m>>2)*64+t*4+(m&3)
// so stage-A's per-lane outputs (d = q*64+t*4+r) are LDS-contiguous.
// ---------------------------------------------------------------------------
__global__ __launch_bounds__(256) void prep_kernel(
    const float* __restrict__ We1, const float* __restrict__ be1,
    const float* __restrict__ g,   const float* __restrict__ bta,
    const float* __restrict__ We2, const float* __restrict__ be2,
    const float* __restrict__ Wq, const float* __restrict__ Wk,
    const float* __restrict__ Wv, const float* __restrict__ Wp,
    ushort* __restrict__ W1G, ushort* __restrict__ B2G, float* __restrict__ tail,
    ushort* __restrict__ WThi, ushort* __restrict__ WTlo)
{
    int t = threadIdx.x;  // 0..255
    if (blockIdx.x != 0) {
        // ---- weight transpose + split (16 blocks per matrix)
        int bx = blockIdx.x - 1;
        int w = bx >> 4, ny = bx & 15;
        const float* W = (w == 0) ? Wq : (w == 1) ? Wk : (w == 2) ? Wv : Wp;
        ushort* dh = WThi + (size_t)w * 65536;
        ushort* dl = WTlo + (size_t)w * 65536;
        int n = ny * 16 + (t >> 4);
        int k0 = (t & 15) * 16;
        ushort hbuf[16], lbuf[16];
#pragma unroll
        for (int kk = 0; kk < 16; ++kk) {
            float v = W[(size_t)(k0 + kk) * 256 + n];
            unsigned int hb = fbits(v) + 0x8000u;
            ushort hi = (ushort)(hb >> 16);
            float res = v - bf2f(hi);
            hbuf[kk] = hi;
            lbuf[kk] = (ushort)((fbits(res) + 0x8000u) >> 16);
        }
        *(short8*)(dh + (size_t)n * 256 + k0)     = *(short8*)&hbuf[0];
        *(short8*)(dh + (size_t)n * 256 + k0 + 8) = *(short8*)&hbuf[8];
        *(short8*)(dl + (size_t)n * 256 + k0)     = *(short8*)&lbuf[0];
        *(short8*)(dl + (size_t)n * 256 + k0 + 8) = *(short8*)&lbuf[8];
        return;
    }

    __shared__ float red[16][256];
    float gd = g[t], bd = bta[t];
#pragma unroll
    for (int h = 0; h < 8; ++h) {
        float w2 = We2[t * 8 + h];
        red[h][t] = gd * w2;
        red[8 + h][t] = bd * w2;
    }
    __syncthreads();
    for (int off = 128; off > 0; off >>= 1) {
        if (t < off) {
#pragma unroll
            for (int row = 0; row < 16; ++row) red[row][t] += red[row][t + off];
        }
        __syncthreads();
    }
    if (t < 8) {
        tail[t] = red[t][0];
        tail[8 + t] = red[8 + t][0] + be2[t];
    }
    if (t >= 16 && t < 32) tail[t] = 0.f;

    // W1G: 8192 entries, with permuted physical-d rows
    for (int idx = t; idx < 8192; idx += 256) {
        int j = idx & 7, lane = (idx >> 3) & 63, tile = idx >> 9;
        int m = lane & 15, q = lane >> 4;
        int k = q * 8 + j;
        int d = (m >> 2) * 64 + tile * 4 + (m & 3);   // permuted (round 7)
        float v = 0.f;
        bool lo = false;
        if (k < 5)        v = We1[k * 256 + d];
        else if (k < 10)  { v = We1[(k - 5) * 256 + d]; lo = true; }
        else if (k < 15)  v = We1[(k - 10) * 256 + d];
        else if (k == 15) v = be1[d];
        else if (k == 16) { v = be1[d]; lo = true; }
        ushort hi = f2bf(v);
        W1G[idx] = lo ? f2bf(v - bf2f(hi)) : hi;
    }
    // B2G: identity d ordering (matches stage-B physical-d reads)
    for (int idx = t; idx < 4096; idx += 256) {
        int j = idx & 7, lane = (idx >> 3) & 63, kc = idx >> 9;
        int n = lane & 15, q = lane >> 4;
        int d = kc * 32 + q * 8 + j;
        ushort out;
        if (n < 8)       out = f2bf(g[d] * We2[d * 8 + n]);
        else if (n == 8) out = 0x3F80;   // 1.0 bf16
        else             out = 0;
        B2G[idx] = out;
    }
}

// ---------------------------------------------------------------------------
// gemm_mfma: C[2048,256] = A @ W + bias (fp32-accurate via bf16 hi/lo).
// If Ct != null, write the (per b,h) transposed layout Ct[(b*256+n)*512+l]
// instead of C (used for K -> Kt; kills the separate transpose kernel).
// ---------------------------------------------------------------------------
__global__ __launch_bounds__(256) void gemm_mfma(
    const float* __restrict__ A0, const ushort* __restrict__ H0,
    const ushort* __restrict__ L0, const float* __restrict__ b0,
    float* __restrict__ C0, float* __restrict__ T0,
    const float* __restrict__ A1, const ushort* __restrict__ H1,
    const ushort* __restrict__ L1, const float* __restrict__ b1,
    float* __restrict__ C1, float* __restrict__ T1,
    const float* __restrict__ A2, const ushort* __restrict__ H2,
    const ushort* __restrict__ L2, const float* __restrict__ b2,
    float* __restrict__ C2, float* __restrict__ T2)
{
    const float* A; const ushort* BH; const ushort* BL;
    const float* bias; float* C; float* Ct;
    if (blockIdx.z == 0)      { A = A0; BH = H0; BL = L0; bias = b0; C = C0; Ct = T0; }
    else if (blockIdx.z == 1) { A = A1; BH = H1; BL = L1; bias = b1; C = C1; Ct = T1; }
    else                      { A = A2; BH = H2; BL = L2; bias = b2; C = C2; Ct = T2; }

    __shared__ ushort Ahi[64][40];
    __shared__ ushort Alo[64][40];

    int tid = threadIdx.x;
    int wv = tid >> 6, lane = tid & 63;
    int m = lane & 15, quad = lane >> 4;
    int bm = blockIdx.x * 64, bn = blockIdx.y * 64;

    int sm = tid >> 2, sg = (tid & 3) * 8;
    const float* Arow = A + (size_t)(bm + sm) * 256 + sg;

    int nrow = bn + wv * 16 + m;
    const ushort* bhp = BH + (size_t)nrow * 256 + quad * 8;
    const ushort* blp = BL + (size_t)nrow * 256 + quad * 8;

    f32x4 acc[4];
#pragma unroll
    for (int mt = 0; mt < 4; ++mt) acc[mt] = (f32x4){0.f, 0.f, 0.f, 0.f};

    for (int k0 = 0; k0 < 256; k0 += 32) {
        float4 a0 = *(const float4*)(Arow + k0);
        float4 a1 = *(const float4*)(Arow + k0 + 4);
        uint2 c0 = cvt_hilo2(a0.x, a0.y);
        uint2 c1 = cvt_hilo2(a0.z, a0.w);
        uint2 c2 = cvt_hilo2(a1.x, a1.y);
        uint2 c3 = cvt_hilo2(a1.z, a1.w);
        if (k0) __syncthreads();
        uint4 hq; hq.x = c0.x; hq.y = c1.x; hq.z = c2.x; hq.w = c3.x;
        uint4 lq; lq.x = c0.y; lq.y = c1.y; lq.z = c2.y; lq.w = c3.y;
        *(uint4*)&Ahi[sm][sg] = hq;
        *(uint4*)&Alo[sm][sg] = lq;
        __syncthreads();

        short8 bhi = *(const short8*)(bhp + k0);
        short8 blo = *(const short8*)(blp + k0);
#pragma unroll
        for (int mt = 0; mt < 4; ++mt) {
            short8 ahi = *(const short8*)&Ahi[mt * 16 + m][quad * 8];
            short8 alo = *(const short8*)&Alo[mt * 16 + m][quad * 8];
            acc[mt] = __builtin_amdgcn_mfma_f32_16x16x32_bf16(ahi, blo, acc[mt], 0, 0, 0);
            acc[mt] = __builtin_amdgcn_mfma_f32_16x16x32_bf16(alo, bhi, acc[mt], 0, 0, 0);
            acc[mt] = __builtin_amdgcn_mfma_f32_16x16x32_bf16(ahi, bhi, acc[mt], 0, 0, 0);
        }
    }

    float bn_bias = bias[nrow];
    if (Ct) {
        // transposed (Kt) epilogue: rows are contiguous along l
        int bb = bm >> 9, l0 = bm & 511;
        float* outp = Ct + ((size_t)(bb * 256 + nrow)) * 512 + l0 + quad * 4;
#pragma unroll
        for (int mt = 0; mt < 4; ++mt) {
            float4 o;
            o.x = acc[mt][0] + bn_bias; o.y = acc[mt][1] + bn_bias;
            o.z = acc[mt][2] + bn_bias; o.w = acc[mt][3] + bn_bias;
            *(float4*)(outp + mt * 16) = o;
        }
    } else {
#pragma unroll
        for (int mt = 0; mt < 4; ++mt) {
#pragma unroll
            for (int r = 0; r < 4; ++r) {
                C[(size_t)(bm + mt * 16 + quad * 4 + r) * 256 + nrow] = acc[mt][r] + bn_bias;
            }
        }
    }
}

// ---------------------------------------------------------------------------
// edge_bias_mfma v3: latency-hiding.
//  - EF loads software-pipelined (iter+1 prefetched before consuming iter)
//  - ef8 built with dword v_perm packs (no 16-bit element inserts)
//  - X writes are ds_write_b128 (paired tiles; W1G d-rows permuted so a
//    lane's 4 outputs are physically consecutive d)
// Math is bit-identical to v2.
// ---------------------------------------------------------------------------
__global__ __launch_bounds__(256) void edge_bias_mfma(
    const float* __restrict__ EF, const ushort* __restrict__ W1G,
    const ushort* __restrict__ B2G, const float* __restrict__ tail,
    ushort* __restrict__ E2)
{
    __shared__ __align__(16) char xt[4 * 16 * 528];  // 33792 B, per-wave tiles
    int tid = threadIdx.x;
    int wv = tid >> 6, lane = tid & 63;
    int q = lane >> 4, n = lane & 15;
    char* myx = xt + wv * (16 * 528);

    int bi = blockIdx.x;            // b*512 + i
    int b = bi >> 9, i = bi & 511;
    size_t rowbase = (size_t)bi * 512;

    short8 w1f[16];
#pragma unroll
    for (int t = 0; t < 16; ++t)
        w1f[t] = *(const short8*)(W1G + (t * 64 + lane) * 8);
    short8 b2f[8];
#pragma unroll
    for (int kc = 0; kc < 8; ++kc)
        b2f[kc] = *(const short8*)(B2G + (kc * 64 + lane) * 8);

    float shv = tail[n];
    float bbv = tail[8 + n];
    const float inv256 = 1.0f / 256.0f;

    const float* efbase = EF + rowbase * 5;
    int pairoff = wv * 16 + n;               // this lane's pair within iter 0

    // prefetch iter 0
    float4 evA = *(const float4*)(efbase + (size_t)pairoff * 5);
    float  evB = efbase[(size_t)pairoff * 5 + 4];

    for (int iter = 0; iter < 8; ++iter) {
        // prefetch next iter's EF while computing this one
        float4 nA; float nB;
        if (iter < 7) {
            const float* p = efbase + (size_t)((iter + 1) * 64 + pairoff) * 5;
            nA = *(const float4*)p;
            nB = p[4];
        }
        int jb = iter * 64 + wv * 16;

        unsigned int hb[5], la[5];
        hb[0] = fbits(evA.x); hb[1] = fbits(evA.y); hb[2] = fbits(evA.z);
        hb[3] = fbits(evA.w); hb[4] = fbits(evB);
        {
            float e0 = evA.x - asf(hb[0] & 0xffff0000u);
            float e1 = evA.y - asf(hb[1] & 0xffff0000u);
            float e2 = evA.z - asf(hb[2] & 0xffff0000u);
            float e3 = evA.w - asf(hb[3] & 0xffff0000u);
            float e4 = evB   - asf(hb[4] & 0xffff0000u);
            la[0] = fbits(e0) + 0x8000u;
            la[1] = fbits(e1) + 0x8000u;
            la[2] = fbits(e2) + 0x8000u;
            la[3] = fbits(e3) + 0x8000u;
            la[4] = fbits(e4) + 0x8000u;
        }
        // q==0 dwords: [h0|h1, h2|h3, h4|h0, h1|h2]; q==1: [h3|h4, l0|l1, l2|l3, l4|ONE]
        unsigned int A0v = packhi(hb[1], hb[0]);
        unsigned int A1v = packhi(hb[3], hb[2]);
        unsigned int A2v = packhi(hb[0], hb[4]);
        unsigned int A3v = packhi(hb[2], hb[1]);
        unsigned int B0v = packhi(hb[4], hb[3]);
        unsigned int B1v = packhi(la[1], la[0]);
        unsigned int B2v = packhi(la[3], la[2]);
        unsigned int B3v = packhi(0x3F800000u, la[4]);
        uint4 efd;
        bool isq0 = (q == 0), isq1 = (q == 1), isq2 = (q == 2);
        efd.x = isq0 ? A0v : isq1 ? B0v : isq2 ? 0x3F80u : 0u;
        efd.y = isq0 ? A1v : isq1 ? B1v : 0u;
        efd.z = isq0 ? A2v : isq1 ? B2v : 0u;
        efd.w = isq0 ? A3v : isq1 ? B3v : 0u;
        short8 ef8;
        __builtin_memcpy(&ef8, &efd, 16);

        // ---- Stage A: X tiles -> LDS (bf16), b128 writes every 2 tiles
        unsigned int pk0 = 0, pk1 = 0;
#pragma unroll
        for (int t = 0; t < 16; ++t) {
            f32x4 z = {0.f, 0.f, 0.f, 0.f};
            f32x4 d1 = __builtin_amdgcn_mfma_f32_16x16x32_bf16(w1f[t], ef8, z, 0, 0, 0);
            float x0 = fmaxf(d1[0], 0.f);
            float x1 = fmaxf(d1[1], 0.f);
            float x2 = fmaxf(d1[2], 0.f);
            float x3 = fmaxf(d1[3], 0.f);
            unsigned int pa = pack_bf16rnd(x0, x1);
            unsigned int pb = pack_bf16rnd(x2, x3);
            if (t & 1) {
                uint4 wq; wq.x = pk0; wq.y = pk1; wq.z = pa; wq.w = pb;
                *(uint4*)(myx + n * 528 + q * 128 + (t - 1) * 8) = wq;
            } else {
                pk0 = pa; pk1 = pb;
            }
        }

        // ---- Stage B: dots+sum via B2, sumsq via X X^T
        f32x4 acc  = {0.f, 0.f, 0.f, 0.f};
        f32x4 acc2 = {0.f, 0.f, 0.f, 0.f};
#pragma unroll
        for (int kc = 0; kc < 8; ++kc) {
            short8 a = *(const short8*)(myx + n * 528 + kc * 64 + q * 16);
            acc  = __builtin_amdgcn_mfma_f32_16x16x32_bf16(a, b2f[kc], acc, 0, 0, 0);
            acc2 = __builtin_amdgcn_mfma_f32_16x16x32_bf16(a, a, acc2, 0, 0, 0);
        }

        // ---- Epilogue: LN fold
        int base = lane & 48;
        float er[4];
#pragma unroll
        for (int r = 0; r < 4; ++r) {
            float sm = __shfl(acc[r], base + 8);
            float sq = __shfl(acc2[r], base + (base >> 2) + r);
            float dot = acc[r];
            float mu = sm * inv256;
            float var = fmaf(-mu, mu, sq * inv256);
            float rs = rsqrtf(var + 1e-5f);
            er[r] = fmaf(dot - mu * shv, rs, bbv);
        }
        if (n < 8) {
            uint2 outv;
            outv.x = pack_bf16rnd(er[0], er[1]);
            outv.y = pack_bf16rnd(er[2], er[3]);
            size_t basep = (((size_t)(b * NH + n) * L_SEQ + i) * L_SEQ) + jb + q * 4;
            *(uint2*)(E2 + basep) = outv;
        }
        evA = nA; evB = nB;
    }
}

// ---------------------------------------------------------------------------
// attn: unchanged from round 4/5/6.
// ---------------------------------------------------------------------------
__global__ __launch_bounds__(256, 3) void attn_kernel(
    const float* __restrict__ Q, const float* __restrict__ Kt,
    const float* __restrict__ V, const ushort* __restrict__ E2,
    const int* __restrict__ MSK, float* __restrict__ Y)
{
    __shared__ float stage[4096];       // 16 KB: K chunk [32][128] / V chunk [128][32]
    __shared__ float pbuf[4][4][520];   // per-wave p rows (fp32)
    __shared__ float qs_t[32][16];      // q transposed: [d][row]

    int bh = blockIdx.x;
    int b = bh >> 3, h = bh & 7;
    int tid = threadIdx.x;
    int wv = tid >> 6, lane = tid & 63;
    int i0 = blockIdx.y * 16;
    int i = i0 + wv * 4;

    const float* Ktb = Kt + (size_t)bh * (HD * L_SEQ);
    const float* Vb  = V + (size_t)b * L_SEQ * D_EMB + h * HD;

    size_t erow = ((size_t)bh * L_SEQ + i) * L_SEQ;
    size_t mrow = ((size_t)b * L_SEQ + i) * L_SEQ;

    unsigned int e2p[4][4];
    int2 mkp[4][4];
#pragma unroll
    for (int r = 0; r < 4; ++r)
#pragma unroll
        for (int c = 0; c < 4; ++c) {
            int j = c * 128 + 2 * lane;
            e2p[r][c] = *(const unsigned int*)(E2 + erow + (size_t)r * L_SEQ + j);
            mkp[r][c] = *(const int2*)(MSK + mrow + (size_t)r * L_SEQ + j);
        }

    if (tid < 128) {
        int r = tid >> 3, c4 = (tid & 7) * 4;
        float4 qv = *(const float4*)(Q + ((size_t)(b * L_SEQ + i0 + r)) * 256 + h * HD + c4);
        qs_t[c4 + 0][r] = qv.x; qs_t[c4 + 1][r] = qv.y;
        qs_t[c4 + 2][r] = qv.z; qs_t[c4 + 3][r] = qv.w;
    }

    float s[4][8];
#pragma unroll
    for (int r = 0; r < 4; ++r)
#pragma unroll
        for (int t = 0; t < 8; ++t) s[r][t] = 0.f;

    for (int c = 0; c < 4; ++c) {
        if (c) __syncthreads();
        {
            int d0 = tid >> 5, jj = (tid & 31) * 4;
#pragma unroll
            for (int p = 0; p < 4; ++p) {
                int d = p * 8 + d0;
                float4 kv = *(const float4*)(Ktb + (size_t)d * L_SEQ + c * 128 + jj);
                *(float4*)&stage[d * 128 + jj] = kv;
            }
        }
        __syncthreads();
        int c2 = c * 2;
#pragma unroll 8
        for (int d = 0; d < HD; ++d) {
            float4 q4 = *(const float4*)&qs_t[d][wv * 4];
            float2 kv = *(const float2*)&stage[d * 128 + 2 * lane];
            s[0][c2]     = fmaf(q4.x, kv.x, s[0][c2]);
            s[0][c2 + 1] = fmaf(q4.x, kv.y, s[0][c2 + 1]);
            s[1][c2]     = fmaf(q4.y, kv.x, s[1][c2]);
            s[1][c2 + 1] = fmaf(q4.y, kv.y, s[1][c2 + 1]);
            s[2][c2]     = fmaf(q4.z, kv.x, s[2][c2]);
            s[2][c2 + 1] = fmaf(q4.z, kv.y, s[2][c2 + 1]);
            s[3][c2]     = fmaf(q4.w, kv.x, s[3][c2]);
            s[3][c2 + 1] = fmaf(q4.w, kv.y, s[3][c2 + 1]);
        }
    }

    const float scl = 0.17677669529663687f;  // 1/sqrt(32)
#pragma unroll
    for (int r = 0; r < 4; ++r) {
        float sv[8];
        float m = -3.0e38f;
#pragma unroll
        for (int idx = 0; idx < 8; ++idx) {
            int c = idx >> 1, u = idx & 1;
            unsigned int pk = e2p[r][c];
            float e = bf2f((ushort)(u ? (pk >> 16) : (pk & 0xffff)));
            int mk = u ? mkp[r][c].y : mkp[r][c].x;
            float v = (mk != 0) ? fmaf(s[r][idx], scl, e) : -1e30f;
            sv[idx] = v;
            m = fmaxf(m, v);
        }
#pragma unroll
        for (int o = 32; o > 0; o >>= 1) m = fmaxf(m, __shfl_xor(m, o));
        float ssum = 0.f;
#pragma unroll
        for (int idx = 0; idx < 8; ++idx) {
            float p = __expf(sv[idx] - m);
            sv[idx] = p;
            ssum += p;
        }
#pragma unroll
        for (int o = 32; o > 0; o >>= 1) ssum += __shfl_xor(ssum, o);
        float inv = 1.0f / ssum;
#pragma unroll
        for (int c = 0; c < 4; ++c) {
            float2 w;
            w.x = sv[c * 2] * inv;
            w.y = sv[c * 2 + 1] * inv;
            *(float2*)&pbuf[wv][r][c * 128 + 2 * lane] = w;
        }
    }

    int dg = lane >> 3, js = lane & 7;
    float4 acc[4];
#pragma unroll
    for (int r = 0; r < 4; ++r) { acc[r].x = 0.f; acc[r].y = 0.f; acc[r].z = 0.f; acc[r].w = 0.f; }

    for (int c = 0; c < 4; ++c) {
        __syncthreads();
        {
            int j0 = tid >> 3, dd = (tid & 7) * 4;
#pragma unroll
            for (int p = 0; p < 4; ++p) {
                int j = p * 32 + j0;
                float4 vv = *(const float4*)(Vb + (size_t)(c * 128 + j) * D_EMB + dd);
                *(float4*)&stage[j * 32 + dd] = vv;
            }
        }
        __syncthreads();
#pragma unroll
        for (int jb = 0; jb < 16; ++jb) {
            int jj = jb * 8 + js;
            float4 v4 = *(const float4*)&stage[jj * 32 + dg * 4];
#pragma unroll
            for (int r = 0; r < 4; ++r) {
                float p = pbuf[wv][r][c * 128 + jj];
                acc[r].x = fmaf(p, v4.x, acc[r].x);
                acc[r].y = fmaf(p, v4.y, acc[r].y);
                acc[r].z = fmaf(p, v4.z, acc[r].z);
                acc[r].w = fmaf(p, v4.w, acc[r].w);
            }
        }
    }

#pragma unroll
    for (int off = 1; off < 8; off <<= 1) {
#pragma unroll
        for (int r = 0; r < 4; ++r) {
            acc[r].x += __shfl_xor(acc[r].x, off);
            acc[r].y += __shfl_xor(acc[r].y, off);
            acc[r].z += __shfl_xor(acc[r].z, off);
            acc[r].w += __shfl_xor(acc[r].w, off);
        }
    }
    if (js == 0) {
#pragma unroll
        for (int r = 0; r < 4; ++r)
            *(float4*)(Y + ((size_t)(b * L_SEQ + i + r)) * 256 + h * HD + dg * 4) = acc[r];
    }
}

// ---------------------------------------------------------------------------
extern "C" void kernel_launch(void* const* d_in, const int* in_sizes, int n_in,
                              void* d_out, int out_size, void* d_ws, size_t ws_size,
                              hipStream_t stream)
{
    const float* key   = (const float*)d_in[0];
    const float* value = (const float*)d_in[1];
    const float* query = (const float*)d_in[2];
    const int*   msk   = (const int*)d_in[3];
    const float* ef    = (const float*)d_in[4];
    const float* Wk  = (const float*)d_in[5];  const float* bk  = (const float*)d_in[6];
    const float* Wq  = (const float*)d_in[7];  const float* bq  = (const float*)d_in[8];
    const float* Wv  = (const float*)d_in[9];  const float* bv  = (const float*)d_in[10];
    const float* Wp  = (const float*)d_in[11]; const float* bp  = (const float*)d_in[12];
    const float* We1 = (const float*)d_in[13]; const float* be1 = (const float*)d_in[14];
    const float* lng = (const float*)d_in[15]; const float* lnb = (const float*)d_in[16];
    const float* We2 = (const float*)d_in[17]; const float* be2 = (const float*)d_in[18];

    const int MTOK = 4 * L_SEQ;          // 2048 rows
    const int NELT = MTOK * D_EMB;       // 524288

    float* ws    = (float*)d_ws;
    float* Qw    = ws;
    float* Vw    = Qw + NELT;
    float* Yw    = Vw + NELT;
    float* Ktw   = Yw + NELT;
    ushort* W1G  = (ushort*)(Ktw + NELT);   // 8192 bf16
    ushort* B2G  = W1G + 8192;              // 4096 bf16
    float* tail  = (float*)(B2G + 4096);    // 32 floats
    ushort* WThi = (ushort*)(tail + 32);    // 4*65536 bf16 (512 KB)
    ushort* WTlo = WThi + 4 * 65536;        // 4*65536 bf16 (512 KB)
    ushort* E2   = WTlo + 4 * 65536;        // 8388608 bf16 (~16.8 MB)

    hipLaunchKernelGGL(prep_kernel, dim3(65), dim3(256), 0, stream,
                       We1, be1, lng, lnb, We2, be2,
                       Wq, Wk, Wv, Wp,
                       W1G, B2G, tail, WThi, WTlo);
    // QKV projections; K writes the transposed Kt layout directly
    hipLaunchKernelGGL(gemm_mfma, dim3(32, 4, 3), dim3(256), 0, stream,
                       query, WThi + 0 * 65536, WTlo + 0 * 65536, bq, Qw,  (float*)nullptr,
                       key,   WThi + 1 * 65536, WTlo + 1 * 65536, bk, (float*)nullptr, Ktw,
                       value, WThi + 2 * 65536, WTlo + 2 * 65536, bv, Vw,  (float*)nullptr);
    hipLaunchKernelGGL(edge_bias_mfma, dim3(2048), dim3(256), 0, stream,
                       ef, W1G, B2G, tail, E2);
    hipLaunchKernelGGL(attn_kernel, dim3(32, 32), dim3(256), 0, stream,
                       Qw, Ktw, Vw, E2, msk, Yw);
    hipLaunchKernelGGL(gemm_mfma, dim3(32, 4, 1), dim3(256), 0, stream,
                       Yw, WThi + 3 * 65536, WTlo + 3 * 65536, bp, (float*)d_out, (float*)nullptr,
                       Yw, WThi + 3 * 65536, WTlo + 3 * 65536, bp, (float*)d_out, (float*)nullptr,
                       Yw, WThi + 3 * 65536, WTlo + 3 * 65536, bp, (float*)d_out, (float*)nullptr);
}